// Round 1
// baseline (1738.834 us; speedup 1.0000x reference)
//
#include <hip/hip_runtime.h>
#include <hip/hip_bf16.h>

#define H 128
#define EFD 8
#define NLAYER 4
#define ZDIM (2*H+EFD)   // 264

__device__ __forceinline__ float sigmoidf_(float x){ return 1.0f/(1.0f+__expf(-x)); }
__device__ __forceinline__ float softplusf_(float x){
    float t = fabsf(x);
    return fmaxf(x, 0.0f) + __logf(1.0f + __expf(-t));
}

// h = relu(x @ W_emb + b_emb)   [N,16]@[16,128]
__global__ void embed_kernel(const float* __restrict__ x, const float* __restrict__ We,
                             const float* __restrict__ be, float* __restrict__ h, int N){
    int idx = blockIdx.x*blockDim.x + threadIdx.x;
    if (idx >= N*H) return;
    int n = idx >> 7, f = idx & 127;
    float a = be[f];
    #pragma unroll
    for (int k=0;k<16;k++) a = fmaf(x[n*16+k], We[k*H+f], a);
    h[idx] = fmaxf(a, 0.f);
}

__global__ void hist_kernel(const int* __restrict__ dstI, int* __restrict__ counts, int E){
    int e = blockIdx.x*blockDim.x + threadIdx.x;
    if (e < E) atomicAdd(&counts[dstI[e]], 1);
}

__global__ __launch_bounds__(1024) void scan1(const int* __restrict__ counts, int* __restrict__ incl,
                                              int* __restrict__ bsums, int N){
    __shared__ int lds[1024];
    int t = threadIdx.x;
    int i = blockIdx.x*1024 + t;
    int v = (i < N) ? counts[i] : 0;
    lds[t] = v;
    __syncthreads();
    for (int off=1; off<1024; off<<=1){
        int add = (t>=off) ? lds[t-off] : 0;
        __syncthreads();
        lds[t] += add;
        __syncthreads();
    }
    if (i < N) incl[i] = lds[t];
    if (t == 1023) bsums[blockIdx.x] = lds[1023];
}

__global__ void scan2(int* bsums, int nb){
    if (threadIdx.x == 0){
        int run = 0;
        for (int b=0;b<nb;b++){ int v = bsums[b]; bsums[b] = run; run += v; }
    }
}

// incl and cursor may alias (read-then-write same index by same thread)
__global__ __launch_bounds__(1024) void scan3(const int* incl, const int* __restrict__ counts,
                                              const int* __restrict__ bsums, int* __restrict__ rowptr,
                                              int* cursor, int N, int E){
    int i = blockIdx.x*1024 + threadIdx.x;
    if (i >= N) return;
    int ex = incl[i] - counts[i] + bsums[blockIdx.x];
    rowptr[i] = ex;
    cursor[i] = ex;
    if (i == N-1) rowptr[N] = E;
}

__global__ void scatter_kernel(const int* __restrict__ srcI, const int* __restrict__ dstI,
                               const float* __restrict__ eattr, int* __restrict__ cursor,
                               int* __restrict__ src_s, float* __restrict__ ea_s, int E){
    int e = blockIdx.x*blockDim.x + threadIdx.x;
    if (e >= E) return;
    int d = dstI[e];
    int pos = atomicAdd(&cursor[d], 1);
    src_s[pos] = srcI[e];
    const float4* s4 = (const float4*)(eattr + (size_t)e*EFD);
    float4* o4 = (float4*)(ea_s + (size_t)pos*EFD);
    o4[0] = s4[0]; o4[1] = s4[1];
}

// Per-layer node tables: one [N,128]@[128,512] GEMM.
// Output row layout: TD[n] = [Fd(128) | Sd(128)] (+biases), TS[n] = [Fs(128) | Ss(128)]
// wave w of the block: w=0 -> Fd(Wf rows 0..127,+bf), w=1 -> Sd(Ws,+bs), w=2 -> Fs(Wf rows 128..255), w=3 -> Ss
__global__ __launch_bounds__(256) void table_gemm(
        const float* __restrict__ h, const float* __restrict__ Wf_l, const float* __restrict__ Ws_l,
        const float* __restrict__ bf_l, const float* __restrict__ bs_l,
        float* __restrict__ TD, float* __restrict__ TS, int N){
    __shared__ float hs[32*128];   // 16KB node tile
    const int t = threadIdx.x;
    const int n0 = blockIdx.x * 32;
    const int nvalid = min(32, N - n0);
    {
        const float4* s4 = (const float4*)(h + (size_t)n0*H);
        float4* d4 = (float4*)hs;
        const int v4 = nvalid*32;
        for (int i=t;i<1024;i+=256) d4[i] = (i<v4) ? s4[i] : make_float4(0.f,0.f,0.f,0.f);
    }
    __syncthreads();
    const int lane = t & 63, w = t >> 6;
    const float* base = (w & 1) ? Ws_l : Wf_l;
    const float* p0 = base + ((w >> 1) ? (H*H) : 0) + lane;
    const float* p1 = p0 + 64;
    float acc0[32], acc1[32];
    #pragma unroll
    for (int n=0;n<32;n++){ acc0[n]=0.f; acc1[n]=0.f; }
    for (int kk=0; kk<H; kk+=4){
        float w00=p0[(kk+0)*H], w01=p0[(kk+1)*H], w02=p0[(kk+2)*H], w03=p0[(kk+3)*H];
        float w10=p1[(kk+0)*H], w11=p1[(kk+1)*H], w12=p1[(kk+2)*H], w13=p1[(kk+3)*H];
        #pragma unroll
        for (int n=0;n<32;n++){
            float4 hv = *(const float4*)&hs[n*H+kk];
            acc0[n] = fmaf(hv.x,w00, fmaf(hv.y,w01, fmaf(hv.z,w02, fmaf(hv.w,w03, acc0[n]))));
            acc1[n] = fmaf(hv.x,w10, fmaf(hv.y,w11, fmaf(hv.z,w12, fmaf(hv.w,w13, acc1[n]))));
        }
    }
    float bia0 = (w==0) ? bf_l[lane] : (w==1) ? bs_l[lane] : 0.f;
    float bia1 = (w==0) ? bf_l[lane+64] : (w==1) ? bs_l[lane+64] : 0.f;
    float* outb = (w < 2) ? TD : TS;
    const int ccol = (w & 1)*128 + lane;
    for (int n=0;n<nvalid;n++){
        float* row = outb + (size_t)(n0+n)*256;
        row[ccol]     = acc0[n] + bia0;
        row[ccol+64]  = acc1[n] + bia1;
    }
}

// One wave per node: gather Fs/Ss rows of incoming-edge sources, gate, accumulate.
// lane k owns features (2k, 2k+1). Edge-attr 8x128 weight cols held in registers.
__global__ __launch_bounds__(256) void agg_kernel(
        const float* __restrict__ TD, const float* __restrict__ TS,
        const int* __restrict__ rowptr, const int* __restrict__ src_s, const float* __restrict__ ea_s,
        const float* __restrict__ Wf_l, const float* __restrict__ Ws_l,
        const float* __restrict__ h, float* __restrict__ xn, int N){
    const int t = threadIdx.x;
    const int k = t & 63;
    const int i = blockIdx.x*4 + (t >> 6);
    if (i >= N) return;
    float2 wef[8], wes[8];
    #pragma unroll
    for (int r=0;r<8;r++){
        wef[r] = *(const float2*)&Wf_l[(2*H + r)*H + 2*k];
        wes[r] = *(const float2*)&Ws_l[(2*H + r)*H + 2*k];
    }
    const float2* td = (const float2*)(TD + (size_t)i*256);
    float2 fd = td[k], sd = td[64+k];
    float accx = 0.f, accy = 0.f;
    const int e1 = rowptr[i+1];
    for (int e = rowptr[i]; e < e1; ++e){
        int j = src_s[e];
        float4 ea0 = *(const float4*)(ea_s + (size_t)e*EFD);
        float4 ea1 = *(const float4*)(ea_s + (size_t)e*EFD + 4);
        const float2* ts = (const float2*)(TS + (size_t)j*256);
        float2 fs = ts[k], ss = ts[64+k];
        float ea[8] = {ea0.x,ea0.y,ea0.z,ea0.w,ea1.x,ea1.y,ea1.z,ea1.w};
        float efx=0.f, efy=0.f, esx=0.f, esy=0.f;
        #pragma unroll
        for (int r=0;r<8;r++){
            efx = fmaf(ea[r], wef[r].x, efx); efy = fmaf(ea[r], wef[r].y, efy);
            esx = fmaf(ea[r], wes[r].x, esx); esy = fmaf(ea[r], wes[r].y, esy);
        }
        float gx = fd.x + fs.x + efx, gy = fd.y + fs.y + efy;
        float px = sd.x + ss.x + esx, py = sd.y + ss.y + esy;
        accx += sigmoidf_(gx) * softplusf_(px);
        accy += sigmoidf_(gy) * softplusf_(py);
    }
    float2 hv = *(const float2*)(h + (size_t)i*H + 2*k);
    float2 o; o.x = accx + hv.x; o.y = accy + hv.y;
    *(float2*)(xn + (size_t)i*H + 2*k) = o;
}

__global__ __launch_bounds__(128) void stats_kernel(const float* __restrict__ xn, double* __restrict__ sums, int N){
    const int f = threadIdx.x;
    const int nb = gridDim.x;
    const int per = (N + nb - 1)/nb;
    const int r0 = blockIdx.x*per;
    const int r1 = min(N, r0+per);
    double s = 0.0, s2 = 0.0;
    for (int r=r0;r<r1;++r){
        float v = xn[(size_t)r*H + f];
        s += v; s2 += (double)v*(double)v;
    }
    atomicAdd(&sums[f], s);
    atomicAdd(&sums[H+f], s2);
}

__global__ void finalize_bn(const double* __restrict__ sums, const float* __restrict__ gamma_l,
                            const float* __restrict__ beta_l, float* __restrict__ scsh, int N){
    int f = threadIdx.x;
    if (f >= H) return;
    double mu = sums[f]/(double)N;
    double var = sums[H+f]/(double)N - mu*mu;
    if (var < 0.0) var = 0.0;
    float sc = (float)((double)gamma_l[f] / sqrt(var + 1e-5));
    scsh[f]   = sc;
    scsh[H+f] = (float)((double)beta_l[f] - mu*(double)sc);
}

__global__ __launch_bounds__(256) void apply_bn(const float* __restrict__ xn, const float* __restrict__ scsh,
                                                float* __restrict__ h, int total4){
    int idx = blockIdx.x*blockDim.x + threadIdx.x;
    if (idx >= total4) return;
    int f = (idx*4) & (H-1);
    float4 v  = *(const float4*)(xn + (size_t)idx*4);
    float4 hh = *(const float4*)(h  + (size_t)idx*4);
    float4 sc = *(const float4*)(scsh + f);
    float4 sh = *(const float4*)(scsh + H + f);
    hh.x += fmaxf(fmaf(v.x, sc.x, sh.x), 0.f);
    hh.y += fmaxf(fmaf(v.y, sc.y, sh.y), 0.f);
    hh.z += fmaxf(fmaf(v.z, sc.z, sh.z), 0.f);
    hh.w += fmaxf(fmaf(v.w, sc.w, sh.w), 0.f);
    *(float4*)(h + (size_t)idx*4) = hh;
}

__global__ void pool_cnt(const int* __restrict__ batch, float* __restrict__ cntf, int N){
    int i = blockIdx.x*blockDim.x + threadIdx.x;
    if (i < N) atomicAdd(&cntf[batch[i]], 1.0f);
}

__global__ void pool_sum(const float* __restrict__ h, const int* __restrict__ batch,
                         float* __restrict__ pooled, int N){
    int idx = blockIdx.x*blockDim.x + threadIdx.x;
    if (idx >= N*64) return;
    int i = idx >> 6, k = idx & 63;
    int g = batch[i];
    float2 v = *(const float2*)(h + (size_t)i*H + 2*k);
    atomicAdd(&pooled[(size_t)g*H + 2*k],     v.x);
    atomicAdd(&pooled[(size_t)g*H + 2*k + 1], v.y);
}

__global__ __launch_bounds__(64) void mlp_kernel(const float* __restrict__ pooled, const float* __restrict__ cntf,
        const float* __restrict__ W1, const float* __restrict__ b1,
        const float* __restrict__ W2, const float* __restrict__ b2,
        const float* __restrict__ Wo, const float* __restrict__ bo, float* __restrict__ out){
    __shared__ float row[128];
    __shared__ float g1[64];
    __shared__ float g2[32];
    int g = blockIdx.x, k = threadIdx.x;
    float inv = 1.0f / fmaxf(cntf[g], 1.0f);
    float2 v = *(const float2*)(pooled + (size_t)g*H + 2*k);
    row[2*k]   = v.x*inv;
    row[2*k+1] = v.y*inv;
    __syncthreads();
    float a = b1[k];
    #pragma unroll 4
    for (int i2=0;i2<128;i2++) a = fmaf(row[i2], W1[i2*64+k], a);
    g1[k] = fmaxf(a, 0.f);
    __syncthreads();
    if (k < 32){
        float b = b2[k];
        #pragma unroll 4
        for (int i2=0;i2<64;i2++) b = fmaf(g1[i2], W2[i2*32+k], b);
        g2[k] = fmaxf(b, 0.f);
    }
    __syncthreads();
    float pgv = (k < 32) ? g2[k]*Wo[k] : 0.f;
    for (int off=32; off>0; off>>=1) pgv += __shfl_down(pgv, off);
    if (k == 0) out[g] = pgv + bo[0];
}

extern "C" void kernel_launch(void* const* d_in, const int* in_sizes, int n_in,
                              void* d_out, int out_size, void* d_ws, size_t ws_size,
                              hipStream_t stream){
    const float* x     = (const float*)d_in[0];
    const int*   eidx  = (const int*)d_in[1];
    const float* eattr = (const float*)d_in[2];
    const int*   batch = (const int*)d_in[3];
    const float* W_emb = (const float*)d_in[4];
    const float* b_emb = (const float*)d_in[5];
    const float* Wf    = (const float*)d_in[6];
    const float* bf    = (const float*)d_in[7];
    const float* Wsm   = (const float*)d_in[8];
    const float* bs    = (const float*)d_in[9];
    const float* gamma = (const float*)d_in[10];
    const float* beta  = (const float*)d_in[11];
    const float* W1    = (const float*)d_in[12];
    const float* b1    = (const float*)d_in[13];
    const float* W2    = (const float*)d_in[14];
    const float* b2    = (const float*)d_in[15];
    const float* Wo    = (const float*)d_in[16];
    const float* bo    = (const float*)d_in[17];
    float* out = (float*)d_out;

    const int N = in_sizes[0]/16;
    const int E = in_sizes[1]/2;
    const int G = out_size;

    const int* srcI = eidx;
    const int* dstI = eidx + E;

    // workspace carve (~184 MB total)
    char* p = (char*)d_ws;
    auto alloc = [&](size_t bytes)->char*{ char* r = p; p += (bytes + 255) & ~255ull; return r; };
    float*  h      = (float*) alloc((size_t)N*H*4);
    float*  xn     = (float*) alloc((size_t)N*H*4);
    float*  TD     = (float*) alloc((size_t)N*2*H*4);
    float*  TS     = (float*) alloc((size_t)N*2*H*4);
    float*  ea_s   = (float*) alloc((size_t)E*EFD*4);
    int*    src_s  = (int*)   alloc((size_t)E*4);
    int*    rowptr = (int*)   alloc((size_t)(N+1)*4);
    int*    cursor = (int*)   alloc((size_t)N*4);   // also incl-scan temp
    int*    counts = (int*)   alloc((size_t)N*4);
    int*    bsums  = (int*)   alloc(256*4);
    double* sums   = (double*)alloc(2*H*8);
    float*  scsh   = (float*) alloc(2*H*4);
    float*  pooled = (float*) alloc((size_t)G*H*4);
    float*  cntf   = (float*) alloc((size_t)G*4);

    const int thr = 256;
    hipMemsetAsync(counts, 0, (size_t)N*4, stream);
    embed_kernel<<<(N*H + thr-1)/thr, thr, 0, stream>>>(x, W_emb, b_emb, h, N);
    hist_kernel<<<(E + thr-1)/thr, thr, 0, stream>>>(dstI, counts, E);
    int nb = (N + 1023)/1024;
    scan1<<<nb, 1024, 0, stream>>>(counts, cursor, bsums, N);
    scan2<<<1, 64, 0, stream>>>(bsums, nb);
    scan3<<<nb, 1024, 0, stream>>>(cursor, counts, bsums, rowptr, cursor, N, E);
    scatter_kernel<<<(E + thr-1)/thr, thr, 0, stream>>>(srcI, dstI, eattr, cursor, src_s, ea_s, E);

    for (int l=0;l<NLAYER;l++){
        const float* Wf_l = Wf  + (size_t)l*ZDIM*H;
        const float* Ws_l = Wsm + (size_t)l*ZDIM*H;
        table_gemm<<<(N+31)/32, 256, 0, stream>>>(h, Wf_l, Ws_l, bf + l*H, bs + l*H, TD, TS, N);
        agg_kernel<<<(N+3)/4, 256, 0, stream>>>(TD, TS, rowptr, src_s, ea_s, Wf_l, Ws_l, h, xn, N);
        hipMemsetAsync(sums, 0, 2*H*8, stream);
        stats_kernel<<<200, 128, 0, stream>>>(xn, sums, N);
        finalize_bn<<<1, 128, 0, stream>>>(sums, gamma + l*H, beta + l*H, scsh, N);
        apply_bn<<<((N*H/4) + thr-1)/thr, thr, 0, stream>>>(xn, scsh, h, N*H/4);
    }

    hipMemsetAsync(pooled, 0, (size_t)G*H*4, stream);
    hipMemsetAsync(cntf, 0, (size_t)G*4, stream);
    pool_cnt<<<(N + thr-1)/thr, thr, 0, stream>>>(batch, cntf, N);
    pool_sum<<<((N*64) + thr-1)/thr, thr, 0, stream>>>(h, batch, pooled, N);
    mlp_kernel<<<G, 64, 0, stream>>>(pooled, cntf, W1, b1, W2, b2, Wo, bo, out);
}

// Round 2
// 1402.378 us; speedup vs baseline: 1.2399x; 1.2399x over previous
//
#include <hip/hip_runtime.h>
#include <hip/hip_bf16.h>

#define H 128
#define EFD 8
#define NLAYER 4
#define ZDIM (2*H+EFD)   // 264

__device__ __forceinline__ float sigmoidf_(float x){ return 1.0f/(1.0f+__expf(-x)); }
__device__ __forceinline__ float softplusf_(float x){
    float t = fabsf(x);
    return fmaxf(x, 0.0f) + __logf(1.0f + __expf(-t));
}

// h = relu(x @ W_emb + b_emb)   [N,16]@[16,128]
__global__ void embed_kernel(const float* __restrict__ x, const float* __restrict__ We,
                             const float* __restrict__ be, float* __restrict__ h, int N){
    int idx = blockIdx.x*blockDim.x + threadIdx.x;
    if (idx >= N*H) return;
    int n = idx >> 7, f = idx & 127;
    float a = be[f];
    #pragma unroll
    for (int k=0;k<16;k++) a = fmaf(x[n*16+k], We[k*H+f], a);
    h[idx] = fmaxf(a, 0.f);
}

__global__ void hist_kernel(const int* __restrict__ dstI, int* __restrict__ counts, int E){
    int e = blockIdx.x*blockDim.x + threadIdx.x;
    if (e < E) atomicAdd(&counts[dstI[e]], 1);
}

__global__ __launch_bounds__(1024) void scan1(const int* __restrict__ counts, int* __restrict__ incl,
                                              int* __restrict__ bsums, int N){
    __shared__ int lds[1024];
    int t = threadIdx.x;
    int i = blockIdx.x*1024 + t;
    int v = (i < N) ? counts[i] : 0;
    lds[t] = v;
    __syncthreads();
    for (int off=1; off<1024; off<<=1){
        int add = (t>=off) ? lds[t-off] : 0;
        __syncthreads();
        lds[t] += add;
        __syncthreads();
    }
    if (i < N) incl[i] = lds[t];
    if (t == 1023) bsums[blockIdx.x] = lds[1023];
}

__global__ void scan2(int* bsums, int nb){
    if (threadIdx.x == 0){
        int run = 0;
        for (int b=0;b<nb;b++){ int v = bsums[b]; bsums[b] = run; run += v; }
    }
}

// incl and cursor may alias (read-then-write same index by same thread)
__global__ __launch_bounds__(1024) void scan3(const int* incl, const int* __restrict__ counts,
                                              const int* __restrict__ bsums, int* __restrict__ rowptr,
                                              int* cursor, int N, int E){
    int i = blockIdx.x*1024 + threadIdx.x;
    if (i >= N) return;
    int ex = incl[i] - counts[i] + bsums[blockIdx.x];
    rowptr[i] = ex;
    cursor[i] = ex;
    if (i == N-1) rowptr[N] = E;
}

__global__ void scatter_kernel(const int* __restrict__ srcI, const int* __restrict__ dstI,
                               const float* __restrict__ eattr, int* __restrict__ cursor,
                               int* __restrict__ src_s, float* __restrict__ ea_s, int E){
    int e = blockIdx.x*blockDim.x + threadIdx.x;
    if (e >= E) return;
    int d = dstI[e];
    int pos = atomicAdd(&cursor[d], 1);
    src_s[pos] = srcI[e];
    const float4* s4 = (const float4*)(eattr + (size_t)e*EFD);
    float4* o4 = (float4*)(ea_s + (size_t)pos*EFD);
    o4[0] = s4[0]; o4[1] = s4[1];
}

// Per-layer node tables: one [N,128]@[128,512] GEMM.
// Output row layout: TD[n] = [Fd(128) | Sd(128)] (+biases), TS[n] = [Fs(128) | Ss(128)]
__global__ __launch_bounds__(256) void table_gemm(
        const float* __restrict__ h, const float* __restrict__ Wf_l, const float* __restrict__ Ws_l,
        const float* __restrict__ bf_l, const float* __restrict__ bs_l,
        float* __restrict__ TD, float* __restrict__ TS, int N){
    __shared__ float hs[32*128];   // 16KB node tile
    const int t = threadIdx.x;
    const int n0 = blockIdx.x * 32;
    const int nvalid = min(32, N - n0);
    {
        const float4* s4 = (const float4*)(h + (size_t)n0*H);
        float4* d4 = (float4*)hs;
        const int v4 = nvalid*32;
        for (int i=t;i<1024;i+=256) d4[i] = (i<v4) ? s4[i] : make_float4(0.f,0.f,0.f,0.f);
    }
    __syncthreads();
    const int lane = t & 63, w = t >> 6;
    const float* base = (w & 1) ? Ws_l : Wf_l;
    const float* p0 = base + ((w >> 1) ? (H*H) : 0) + lane;
    const float* p1 = p0 + 64;
    float acc0[32], acc1[32];
    #pragma unroll
    for (int n=0;n<32;n++){ acc0[n]=0.f; acc1[n]=0.f; }
    for (int kk=0; kk<H; kk+=4){
        float w00=p0[(kk+0)*H], w01=p0[(kk+1)*H], w02=p0[(kk+2)*H], w03=p0[(kk+3)*H];
        float w10=p1[(kk+0)*H], w11=p1[(kk+1)*H], w12=p1[(kk+2)*H], w13=p1[(kk+3)*H];
        #pragma unroll
        for (int n=0;n<32;n++){
            float4 hv = *(const float4*)&hs[n*H+kk];
            acc0[n] = fmaf(hv.x,w00, fmaf(hv.y,w01, fmaf(hv.z,w02, fmaf(hv.w,w03, acc0[n]))));
            acc1[n] = fmaf(hv.x,w10, fmaf(hv.y,w11, fmaf(hv.z,w12, fmaf(hv.w,w13, acc1[n]))));
        }
    }
    float bia0 = (w==0) ? bf_l[lane] : (w==1) ? bs_l[lane] : 0.f;
    float bia1 = (w==0) ? bf_l[lane+64] : (w==1) ? bs_l[lane+64] : 0.f;
    float* outb = (w < 2) ? TD : TS;
    const int ccol = (w & 1)*128 + lane;
    for (int n=0;n<nvalid;n++){
        float* row = outb + (size_t)(n0+n)*256;
        row[ccol]     = acc0[n] + bia0;
        row[ccol+64]  = acc1[n] + bia1;
    }
}

// One wave per node. Edge-weight matrices staged in LDS then held in registers.
// Scalarized edge loop: rowptr bounds, src id, and edge-attr are wave-uniform (SGPR).
__global__ __launch_bounds__(256, 4) void agg_kernel(
        const float* __restrict__ TD, const float* __restrict__ TS,
        const int* __restrict__ rowptr, const int* __restrict__ src_s, const float* __restrict__ ea_s,
        const float* __restrict__ Wf_l, const float* __restrict__ Ws_l,
        const float* __restrict__ h, float* __restrict__ xn, int N){
    __shared__ float wE[2048];   // [0..7][128]=Wf edge rows, [8..15][128]=Ws edge rows (8KB)
    const int t = threadIdx.x;
    {
        const float4* a = (const float4*)(Wf_l + 2*H*H);
        const float4* b = (const float4*)(Ws_l + 2*H*H);
        float4* dst = (float4*)wE;
        dst[t]       = a[t];
        dst[256 + t] = b[t];
    }
    __syncthreads();
    const int k = t & 63;
    const int i = blockIdx.x*4 + (t >> 6);
    if (i >= N) return;
    float2 wef[8], wes[8];
    #pragma unroll
    for (int r=0;r<8;r++){
        wef[r] = *(const float2*)&wE[r*128 + 2*k];
        wes[r] = *(const float2*)&wE[1024 + r*128 + 2*k];
    }
    const float2* td = (const float2*)(TD + (size_t)i*256);
    float2 fd = td[k], sd = td[64+k];
    float accx = 0.f, accy = 0.f;
    const int e0 = __builtin_amdgcn_readfirstlane(rowptr[i]);
    const int e1 = __builtin_amdgcn_readfirstlane(rowptr[i+1]);
    for (int e = e0; e < e1; ++e){
        const int j = __builtin_amdgcn_readfirstlane(src_s[e]);
        const float* eap = ea_s + (size_t)e*EFD;
        float ea[8];
        #pragma unroll
        for (int r=0;r<8;r++) ea[r] = eap[r];
        const float2* ts = (const float2*)(TS + (size_t)j*256);
        float2 fs = ts[k], ss = ts[64+k];
        float efx=0.f, efy=0.f, esx=0.f, esy=0.f;
        #pragma unroll
        for (int r=0;r<8;r++){
            efx = fmaf(ea[r], wef[r].x, efx); efy = fmaf(ea[r], wef[r].y, efy);
            esx = fmaf(ea[r], wes[r].x, esx); esy = fmaf(ea[r], wes[r].y, esy);
        }
        float gx = fd.x + fs.x + efx, gy = fd.y + fs.y + efy;
        float px = sd.x + ss.x + esx, py = sd.y + ss.y + esy;
        accx += sigmoidf_(gx) * softplusf_(px);
        accy += sigmoidf_(gy) * softplusf_(py);
    }
    float2 hv = *(const float2*)(h + (size_t)i*H + 2*k);
    float2 o; o.x = accx + hv.x; o.y = accy + hv.y;
    *(float2*)(xn + (size_t)i*H + 2*k) = o;
}

__global__ __launch_bounds__(256) void stats_kernel(const float* __restrict__ xn, double* __restrict__ sums, int N){
    __shared__ double l1[128], l2[128];
    const int f = threadIdx.x & 127;
    const int half = threadIdx.x >> 7;
    const int nb = gridDim.x;
    const int per = (N + nb - 1)/nb;
    const int r0 = blockIdx.x*per;
    const int r1 = min(N, r0+per);
    double s = 0.0, s2 = 0.0;
    for (int r=r0+half; r<r1; r+=2){
        float v = xn[(size_t)r*H + f];
        s += v; s2 += (double)v*(double)v;
    }
    if (half == 1){ l1[f] = s; l2[f] = s2; }
    __syncthreads();
    if (half == 0){
        s += l1[f]; s2 += l2[f];
        atomicAdd(&sums[f], s);
        atomicAdd(&sums[H+f], s2);
    }
}

__global__ void finalize_bn(double* __restrict__ sums, const float* __restrict__ gamma_l,
                            const float* __restrict__ beta_l, float* __restrict__ scsh, int N){
    int f = threadIdx.x;
    if (f >= H) return;
    double mu = sums[f]/(double)N;
    double var = sums[H+f]/(double)N - mu*mu;
    if (var < 0.0) var = 0.0;
    float sc = (float)((double)gamma_l[f] / sqrt(var + 1e-5));
    scsh[f]   = sc;
    scsh[H+f] = (float)((double)beta_l[f] - mu*(double)sc);
    sums[f] = 0.0;       // reset for next layer
    sums[H+f] = 0.0;
}

__global__ __launch_bounds__(256) void apply_bn(const float* __restrict__ xn, const float* __restrict__ scsh,
                                                float* __restrict__ h, int total4){
    int idx = blockIdx.x*blockDim.x + threadIdx.x;
    if (idx >= total4) return;
    int f = (idx*4) & (H-1);
    float4 v  = *(const float4*)(xn + (size_t)idx*4);
    float4 hh = *(const float4*)(h  + (size_t)idx*4);
    float4 sc = *(const float4*)(scsh + f);
    float4 sh = *(const float4*)(scsh + H + f);
    hh.x += fmaxf(fmaf(v.x, sc.x, sh.x), 0.f);
    hh.y += fmaxf(fmaf(v.y, sc.y, sh.y), 0.f);
    hh.z += fmaxf(fmaf(v.z, sc.z, sh.z), 0.f);
    hh.w += fmaxf(fmaf(v.w, sc.w, sh.w), 0.f);
    *(float4*)(h + (size_t)idx*4) = hh;
}

// One block per graph: binary-search sorted batch for the segment, mean-pool, then MLP.
__global__ __launch_bounds__(128) void pool_mlp_kernel(const float* __restrict__ h, const int* __restrict__ batch,
        const float* __restrict__ W1, const float* __restrict__ b1,
        const float* __restrict__ W2, const float* __restrict__ b2,
        const float* __restrict__ Wo, const float* __restrict__ bo,
        float* __restrict__ out, int N){
    __shared__ float row[128];
    __shared__ float g1[64];
    __shared__ float g2[32];
    const int g = blockIdx.x;
    const int t = threadIdx.x;
    int lo = 0, hi = N;
    while (lo < hi){ int m = (lo+hi)>>1; if (batch[m] < g) lo = m+1; else hi = m; }
    const int s0 = lo;
    hi = N;
    while (lo < hi){ int m = (lo+hi)>>1; if (batch[m] < g+1) lo = m+1; else hi = m; }
    const int s1 = lo;
    float acc = 0.f;
    for (int r = s0; r < s1; ++r) acc += h[(size_t)r*H + t];
    const float inv = 1.0f/fmaxf((float)(s1-s0), 1.0f);
    row[t] = acc*inv;
    __syncthreads();
    if (t < 64){
        float a = b1[t];
        #pragma unroll 4
        for (int i2=0;i2<128;i2++) a = fmaf(row[i2], W1[i2*64+t], a);
        g1[t] = fmaxf(a, 0.f);
    }
    __syncthreads();
    if (t < 32){
        float b = b2[t];
        #pragma unroll 4
        for (int i2=0;i2<64;i2++) b = fmaf(g1[i2], W2[i2*32+t], b);
        g2[t] = fmaxf(b, 0.f);
    }
    __syncthreads();
    if (t < 64){
        float p = (t < 32) ? g2[t]*Wo[t] : 0.f;
        for (int off=32; off>0; off>>=1) p += __shfl_down(p, off);
        if (t == 0) out[g] = p + bo[0];
    }
}

extern "C" void kernel_launch(void* const* d_in, const int* in_sizes, int n_in,
                              void* d_out, int out_size, void* d_ws, size_t ws_size,
                              hipStream_t stream){
    const float* x     = (const float*)d_in[0];
    const int*   eidx  = (const int*)d_in[1];
    const float* eattr = (const float*)d_in[2];
    const int*   batch = (const int*)d_in[3];
    const float* W_emb = (const float*)d_in[4];
    const float* b_emb = (const float*)d_in[5];
    const float* Wf    = (const float*)d_in[6];
    const float* bf    = (const float*)d_in[7];
    const float* Wsm   = (const float*)d_in[8];
    const float* bs    = (const float*)d_in[9];
    const float* gamma = (const float*)d_in[10];
    const float* beta  = (const float*)d_in[11];
    const float* W1    = (const float*)d_in[12];
    const float* b1    = (const float*)d_in[13];
    const float* W2    = (const float*)d_in[14];
    const float* b2    = (const float*)d_in[15];
    const float* Wo    = (const float*)d_in[16];
    const float* bo    = (const float*)d_in[17];
    float* out = (float*)d_out;

    const int N = in_sizes[0]/16;
    const int E = in_sizes[1]/2;
    const int G = out_size;

    const int* srcI = eidx;
    const int* dstI = eidx + E;

    char* p = (char*)d_ws;
    auto alloc = [&](size_t bytes)->char*{ char* r = p; p += (bytes + 255) & ~255ull; return r; };
    float*  h      = (float*) alloc((size_t)N*H*4);
    float*  xn     = (float*) alloc((size_t)N*H*4);
    float*  TD     = (float*) alloc((size_t)N*2*H*4);
    float*  TS     = (float*) alloc((size_t)N*2*H*4);
    float*  ea_s   = (float*) alloc((size_t)E*EFD*4);
    int*    src_s  = (int*)   alloc((size_t)E*4);
    int*    rowptr = (int*)   alloc((size_t)(N+1)*4);
    int*    cursor = (int*)   alloc((size_t)N*4);   // also incl-scan temp
    int*    counts = (int*)   alloc((size_t)N*4);
    int*    bsums  = (int*)   alloc(256*4);
    double* sums   = (double*)alloc(2*H*8);
    float*  scsh   = (float*) alloc(2*H*4);

    const int thr = 256;
    hipMemsetAsync(counts, 0, (size_t)N*4, stream);
    hipMemsetAsync(sums, 0, 2*H*8, stream);
    embed_kernel<<<(N*H + thr-1)/thr, thr, 0, stream>>>(x, W_emb, b_emb, h, N);
    hist_kernel<<<(E + thr-1)/thr, thr, 0, stream>>>(dstI, counts, E);
    int nb = (N + 1023)/1024;
    scan1<<<nb, 1024, 0, stream>>>(counts, cursor, bsums, N);
    scan2<<<1, 64, 0, stream>>>(bsums, nb);
    scan3<<<nb, 1024, 0, stream>>>(cursor, counts, bsums, rowptr, cursor, N, E);
    scatter_kernel<<<(E + thr-1)/thr, thr, 0, stream>>>(srcI, dstI, eattr, cursor, src_s, ea_s, E);

    for (int l=0;l<NLAYER;l++){
        const float* Wf_l = Wf  + (size_t)l*ZDIM*H;
        const float* Ws_l = Wsm + (size_t)l*ZDIM*H;
        table_gemm<<<(N+31)/32, 256, 0, stream>>>(h, Wf_l, Ws_l, bf + l*H, bs + l*H, TD, TS, N);
        agg_kernel<<<(N+3)/4, 256, 0, stream>>>(TD, TS, rowptr, src_s, ea_s, Wf_l, Ws_l, h, xn, N);
        stats_kernel<<<256, 256, 0, stream>>>(xn, sums, N);
        finalize_bn<<<1, 128, 0, stream>>>(sums, gamma + l*H, beta + l*H, scsh, N);
        apply_bn<<<((N*H/4) + thr-1)/thr, thr, 0, stream>>>(xn, scsh, h, N*H/4);
    }

    pool_mlp_kernel<<<G, 128, 0, stream>>>(h, batch, W1, b1, W2, b2, Wo, bo, out, N);
}

// Round 3
// 1344.374 us; speedup vs baseline: 1.2934x; 1.0431x over previous
//
#include <hip/hip_runtime.h>
#include <hip/hip_bf16.h>

#define H 128
#define EFD 8
#define NLAYER 4
#define ZDIM (2*H+EFD)   // 264

typedef float f32x2 __attribute__((ext_vector_type(2)));

// packed fp32 fma with src0 broadcast from low/high half (VOP3P op_sel)
#define PKFMA_LO(acc, a, b) asm("v_pk_fma_f32 %0, %1, %2, %0 op_sel:[0,0,0] op_sel_hi:[0,1,1]" : "+v"(acc) : "v"(a), "v"(b))
#define PKFMA_HI(acc, a, b) asm("v_pk_fma_f32 %0, %1, %2, %0 op_sel:[1,0,0] op_sel_hi:[1,1,1]" : "+v"(acc) : "v"(a), "v"(b))

#define L2E 1.44269504088896340736f
#define LN2 0.69314718055994530942f

// h = relu(x @ W_emb + b_emb)   [N,16]@[16,128]
__global__ void embed_kernel(const float* __restrict__ x, const float* __restrict__ We,
                             const float* __restrict__ be, float* __restrict__ h, int N){
    int idx = blockIdx.x*blockDim.x + threadIdx.x;
    if (idx >= N*H) return;
    int n = idx >> 7, f = idx & 127;
    float a = be[f];
    #pragma unroll
    for (int k=0;k<16;k++) a = fmaf(x[n*16+k], We[k*H+f], a);
    h[idx] = fmaxf(a, 0.f);
}

__global__ void hist_kernel(const int* __restrict__ dstI, int* __restrict__ counts, int E){
    int e = blockIdx.x*blockDim.x + threadIdx.x;
    if (e < E) atomicAdd(&counts[dstI[e]], 1);
}

__global__ __launch_bounds__(1024) void scan1(const int* __restrict__ counts, int* __restrict__ incl,
                                              int* __restrict__ bsums, int N){
    __shared__ int lds[1024];
    int t = threadIdx.x;
    int i = blockIdx.x*1024 + t;
    int v = (i < N) ? counts[i] : 0;
    lds[t] = v;
    __syncthreads();
    for (int off=1; off<1024; off<<=1){
        int add = (t>=off) ? lds[t-off] : 0;
        __syncthreads();
        lds[t] += add;
        __syncthreads();
    }
    if (i < N) incl[i] = lds[t];
    if (t == 1023) bsums[blockIdx.x] = lds[1023];
}

__global__ void scan2(int* bsums, int nb){
    if (threadIdx.x == 0){
        int run = 0;
        for (int b=0;b<nb;b++){ int v = bsums[b]; bsums[b] = run; run += v; }
    }
}

__global__ __launch_bounds__(1024) void scan3(const int* incl, const int* __restrict__ counts,
                                              const int* __restrict__ bsums, int* __restrict__ rowptr,
                                              int* cursor, int N, int E){
    int i = blockIdx.x*1024 + threadIdx.x;
    if (i >= N) return;
    int ex = incl[i] - counts[i] + bsums[blockIdx.x];
    rowptr[i] = ex;
    cursor[i] = ex;
    if (i == N-1) rowptr[N] = E;
}

__global__ void scatter_kernel(const int* __restrict__ srcI, const int* __restrict__ dstI,
                               const float* __restrict__ eattr, int* __restrict__ cursor,
                               int* __restrict__ src_s, float* __restrict__ ea_s, int E){
    int e = blockIdx.x*blockDim.x + threadIdx.x;
    if (e >= E) return;
    int d = dstI[e];
    int pos = atomicAdd(&cursor[d], 1);
    src_s[pos] = srcI[e];
    const float4* s4 = (const float4*)(eattr + (size_t)e*EFD);
    float4* o4 = (float4*)(ea_s + (size_t)pos*EFD);
    o4[0] = s4[0]; o4[1] = s4[1];
}

// Per-layer node tables (pre-scaled by log2e): wave w handles nodes w*8..w*8+7 of the
// 32-node tile, lane owns cols (2l,2l+1) of each of the 4 tables {Fd,Sd,Fs,Ss}.
// TD[n] = [Fd|Sd] (+scaled biases), TS[n] = [Fs|Ss].
__global__ __launch_bounds__(256, 3) void table_gemm(
        const float* __restrict__ h, const float* __restrict__ Wf_l, const float* __restrict__ Ws_l,
        const float* __restrict__ bf_l, const float* __restrict__ bs_l,
        float* __restrict__ TD, float* __restrict__ TS, int N){
    __shared__ float hs[32*128];   // 16KB node tile
    const int t = threadIdx.x;
    const int n0 = blockIdx.x * 32;
    const int nvalid = min(32, N - n0);
    {
        const float4* s4 = (const float4*)(h + (size_t)n0*H);
        float4* d4 = (float4*)hs;
        const int v4 = nvalid*32;
        for (int i=t;i<1024;i+=256) d4[i] = (i<v4) ? s4[i] : make_float4(0.f,0.f,0.f,0.f);
    }
    __syncthreads();
    const int l = t & 63, w = t >> 6;
    const int c = 2*l;
    const float* wF = Wf_l + c;
    const float* wS = Ws_l + c;
    f32x2 acc[8][4];
    f32x2 bfv = *(const f32x2*)(bf_l + c);
    f32x2 bsv = *(const f32x2*)(bs_l + c);
    f32x2 zz = {0.f, 0.f};
    #pragma unroll
    for (int n=0;n<8;n++){ acc[n][0]=bfv; acc[n][1]=bsv; acc[n][2]=zz; acc[n][3]=zz; }
    const float* hrow = hs + (w*8)*H;
    for (int kk=0; kk<H; kk+=4){
        f32x2 wFd[4], wSd[4], wFs[4], wSs[4];
        #pragma unroll
        for (int q=0;q<4;q++){
            wFd[q] = *(const f32x2*)(wF + (kk+q)*H);
            wSd[q] = *(const f32x2*)(wS + (kk+q)*H);
            wFs[q] = *(const f32x2*)(wF + (H+kk+q)*H);
            wSs[q] = *(const f32x2*)(wS + (H+kk+q)*H);
        }
        #pragma unroll
        for (int n=0;n<8;n++){
            f32x2 hA = *(const f32x2*)(hrow + n*H + kk);
            f32x2 hB = *(const f32x2*)(hrow + n*H + kk + 2);
            PKFMA_LO(acc[n][0], hA, wFd[0]); PKFMA_HI(acc[n][0], hA, wFd[1]);
            PKFMA_LO(acc[n][0], hB, wFd[2]); PKFMA_HI(acc[n][0], hB, wFd[3]);
            PKFMA_LO(acc[n][1], hA, wSd[0]); PKFMA_HI(acc[n][1], hA, wSd[1]);
            PKFMA_LO(acc[n][1], hB, wSd[2]); PKFMA_HI(acc[n][1], hB, wSd[3]);
            PKFMA_LO(acc[n][2], hA, wFs[0]); PKFMA_HI(acc[n][2], hA, wFs[1]);
            PKFMA_LO(acc[n][2], hB, wFs[2]); PKFMA_HI(acc[n][2], hB, wFs[3]);
            PKFMA_LO(acc[n][3], hA, wSs[0]); PKFMA_HI(acc[n][3], hA, wSs[1]);
            PKFMA_LO(acc[n][3], hB, wSs[2]); PKFMA_HI(acc[n][3], hB, wSs[3]);
        }
    }
    const f32x2 l2e2 = {L2E, L2E};
    #pragma unroll
    for (int n=0;n<8;n++){
        int nl = w*8 + n;
        if (nl < nvalid){
            f32x2* tdr = (f32x2*)(TD + (size_t)(n0+nl)*256);
            f32x2* tsr = (f32x2*)(TS + (size_t)(n0+nl)*256);
            tdr[l]    = acc[n][0]*l2e2;
            tdr[64+l] = acc[n][1]*l2e2;
            tsr[l]    = acc[n][2]*l2e2;
            tsr[64+l] = acc[n][3]*l2e2;
        }
    }
}

// One wave per node; weights pinned in VGPRs; packed fp32 fma; exp2-domain gates;
// one-edge-ahead software pipeline; SGPR-base gathers.
__global__ __launch_bounds__(256, 4) void agg_kernel(
        const float* __restrict__ TD, const float* __restrict__ TS,
        const int* __restrict__ rowptr, const int* __restrict__ src_s, const float* __restrict__ ea_s,
        const float* __restrict__ Wf_l, const float* __restrict__ Ws_l,
        const float* __restrict__ h, float* __restrict__ xn, int N){
    __shared__ float wE[2048];   // [8][128] Wf edge rows, then [8][128] Ws edge rows (scaled by log2e)
    const int t = threadIdx.x;
    {
        const float4* a = (const float4*)(Wf_l + 2*H*H);
        const float4* b = (const float4*)(Ws_l + 2*H*H);
        float4 va = a[t], vb = b[t];
        va.x*=L2E; va.y*=L2E; va.z*=L2E; va.w*=L2E;
        vb.x*=L2E; vb.y*=L2E; vb.z*=L2E; vb.w*=L2E;
        ((float4*)wE)[t] = va;
        ((float4*)wE)[256 + t] = vb;
    }
    __syncthreads();
    const int k = t & 63;
    const int i = blockIdx.x*4 + (t >> 6);
    if (i >= N) return;
    f32x2 wef2[8], wes2[8];
    #pragma unroll
    for (int r=0;r<8;r++){
        wef2[r] = *(const f32x2*)&wE[r*128 + 2*k];
        wes2[r] = *(const f32x2*)&wE[1024 + r*128 + 2*k];
    }
    #pragma unroll
    for (int r=0;r<8;r++) asm volatile("" : "+v"(wef2[r]), "+v"(wes2[r]));
    const f32x2* td = (const f32x2*)(TD + ((size_t)i << 8));
    f32x2 fd2 = td[k], sd2 = td[64+k];
    f32x2 acc = {0.f, 0.f};
    const int e0 = __builtin_amdgcn_readfirstlane(rowptr[i]);
    const int e1 = __builtin_amdgcn_readfirstlane(rowptr[i+1]);
    int j = __builtin_amdgcn_readfirstlane(src_s[e0]);
    const float* eb = ea_s + (size_t)e0*EFD;
    f32x2 ea0 = *(const f32x2*)(eb);
    f32x2 ea1 = *(const f32x2*)(eb+2);
    f32x2 ea2 = *(const f32x2*)(eb+4);
    f32x2 ea3 = *(const f32x2*)(eb+6);
    for (int e = e0; e < e1; ++e){
        const float* tsrow = TS + ((size_t)(unsigned)j << 8);
        f32x2 fs2 = *(const f32x2*)(tsrow + 2*k);
        f32x2 ss2 = *(const f32x2*)(tsrow + 128 + 2*k);
        const int en = (e+1 < e1) ? (e+1) : e;
        const int jn = __builtin_amdgcn_readfirstlane(src_s[en]);
        const float* ebn = ea_s + (size_t)en*EFD;
        f32x2 na0 = *(const f32x2*)(ebn);
        f32x2 na1 = *(const f32x2*)(ebn+2);
        f32x2 na2 = *(const f32x2*)(ebn+4);
        f32x2 na3 = *(const f32x2*)(ebn+6);
        f32x2 ef = fd2, es = sd2;
        PKFMA_LO(ef, ea0, wef2[0]); PKFMA_HI(ef, ea0, wef2[1]);
        PKFMA_LO(ef, ea1, wef2[2]); PKFMA_HI(ef, ea1, wef2[3]);
        PKFMA_LO(ef, ea2, wef2[4]); PKFMA_HI(ef, ea2, wef2[5]);
        PKFMA_LO(ef, ea3, wef2[6]); PKFMA_HI(ef, ea3, wef2[7]);
        PKFMA_LO(es, ea0, wes2[0]); PKFMA_HI(es, ea0, wes2[1]);
        PKFMA_LO(es, ea1, wes2[2]); PKFMA_HI(es, ea1, wes2[3]);
        PKFMA_LO(es, ea2, wes2[4]); PKFMA_HI(es, ea2, wes2[5]);
        PKFMA_LO(es, ea3, wes2[6]); PKFMA_HI(es, ea3, wes2[7]);
        f32x2 g = ef + fs2;
        f32x2 p = es + ss2;
        float sx = __builtin_amdgcn_rcpf(1.0f + __builtin_amdgcn_exp2f(-g.x));
        float sy = __builtin_amdgcn_rcpf(1.0f + __builtin_amdgcn_exp2f(-g.y));
        float tx = fmaxf(p.x, 0.f) + __builtin_amdgcn_logf(1.0f + __builtin_amdgcn_exp2f(-fabsf(p.x)));
        float ty = fmaxf(p.y, 0.f) + __builtin_amdgcn_logf(1.0f + __builtin_amdgcn_exp2f(-fabsf(p.y)));
        acc.x = fmaf(sx*tx, LN2, acc.x);
        acc.y = fmaf(sy*ty, LN2, acc.y);
        j = jn; ea0 = na0; ea1 = na1; ea2 = na2; ea3 = na3;
    }
    f32x2 hv = *(const f32x2*)(h + ((size_t)i << 7) + 2*k);
    f32x2 o = acc + hv;
    *(f32x2*)(xn + ((size_t)i << 7) + 2*k) = o;
}

__global__ __launch_bounds__(256) void stats_kernel(const float* __restrict__ xn, double* __restrict__ sums, int N){
    __shared__ double l1[128], l2[128];
    const int f = threadIdx.x & 127;
    const int half = threadIdx.x >> 7;
    const int nb = gridDim.x;
    const int per = (N + nb - 1)/nb;
    const int r0 = blockIdx.x*per;
    const int r1 = min(N, r0+per);
    double s = 0.0, s2 = 0.0;
    for (int r=r0+half; r<r1; r+=2){
        float v = xn[(size_t)r*H + f];
        s += v; s2 += (double)v*(double)v;
    }
    if (half == 1){ l1[f] = s; l2[f] = s2; }
    __syncthreads();
    if (half == 0){
        s += l1[f]; s2 += l2[f];
        atomicAdd(&sums[f], s);
        atomicAdd(&sums[H+f], s2);
    }
}

__global__ void finalize_bn(double* __restrict__ sums, const float* __restrict__ gamma_l,
                            const float* __restrict__ beta_l, float* __restrict__ scsh, int N){
    int f = threadIdx.x;
    if (f >= H) return;
    double mu = sums[f]/(double)N;
    double var = sums[H+f]/(double)N - mu*mu;
    if (var < 0.0) var = 0.0;
    float sc = (float)((double)gamma_l[f] / sqrt(var + 1e-5));
    scsh[f]   = sc;
    scsh[H+f] = (float)((double)beta_l[f] - mu*(double)sc);
    sums[f] = 0.0;       // reset for next layer
    sums[H+f] = 0.0;
}

__global__ __launch_bounds__(256) void apply_bn(const float* __restrict__ xn, const float* __restrict__ scsh,
                                                float* __restrict__ h, int total4){
    int idx = blockIdx.x*blockDim.x + threadIdx.x;
    if (idx >= total4) return;
    int f = (idx*4) & (H-1);
    float4 v  = *(const float4*)(xn + (size_t)idx*4);
    float4 hh = *(const float4*)(h  + (size_t)idx*4);
    float4 sc = *(const float4*)(scsh + f);
    float4 sh = *(const float4*)(scsh + H + f);
    hh.x += fmaxf(fmaf(v.x, sc.x, sh.x), 0.f);
    hh.y += fmaxf(fmaf(v.y, sc.y, sh.y), 0.f);
    hh.z += fmaxf(fmaf(v.z, sc.z, sh.z), 0.f);
    hh.w += fmaxf(fmaf(v.w, sc.w, sh.w), 0.f);
    *(float4*)(h + (size_t)idx*4) = hh;
}

// One block per graph: binary-search sorted batch for the segment, mean-pool, then MLP.
__global__ __launch_bounds__(128) void pool_mlp_kernel(const float* __restrict__ h, const int* __restrict__ batch,
        const float* __restrict__ W1, const float* __restrict__ b1,
        const float* __restrict__ W2, const float* __restrict__ b2,
        const float* __restrict__ Wo, const float* __restrict__ bo,
        float* __restrict__ out, int N){
    __shared__ float row[128];
    __shared__ float g1[64];
    __shared__ float g2[32];
    const int g = blockIdx.x;
    const int t = threadIdx.x;
    int lo = 0, hi = N;
    while (lo < hi){ int m = (lo+hi)>>1; if (batch[m] < g) lo = m+1; else hi = m; }
    const int s0 = lo;
    hi = N;
    while (lo < hi){ int m = (lo+hi)>>1; if (batch[m] < g+1) lo = m+1; else hi = m; }
    const int s1 = lo;
    float acc = 0.f;
    for (int r = s0; r < s1; ++r) acc += h[(size_t)r*H + t];
    const float inv = 1.0f/fmaxf((float)(s1-s0), 1.0f);
    row[t] = acc*inv;
    __syncthreads();
    if (t < 64){
        float a = b1[t];
        #pragma unroll 4
        for (int i2=0;i2<128;i2++) a = fmaf(row[i2], W1[i2*64+t], a);
        g1[t] = fmaxf(a, 0.f);
    }
    __syncthreads();
    if (t < 32){
        float b = b2[t];
        #pragma unroll 4
        for (int i2=0;i2<64;i2++) b = fmaf(g1[i2], W2[i2*32+t], b);
        g2[t] = fmaxf(b, 0.f);
    }
    __syncthreads();
    if (t < 64){
        float p = (t < 32) ? g2[t]*Wo[t] : 0.f;
        for (int off=32; off>0; off>>=1) p += __shfl_down(p, off);
        if (t == 0) out[g] = p + bo[0];
    }
}

extern "C" void kernel_launch(void* const* d_in, const int* in_sizes, int n_in,
                              void* d_out, int out_size, void* d_ws, size_t ws_size,
                              hipStream_t stream){
    const float* x     = (const float*)d_in[0];
    const int*   eidx  = (const int*)d_in[1];
    const float* eattr = (const float*)d_in[2];
    const int*   batch = (const int*)d_in[3];
    const float* W_emb = (const float*)d_in[4];
    const float* b_emb = (const float*)d_in[5];
    const float* Wf    = (const float*)d_in[6];
    const float* bf    = (const float*)d_in[7];
    const float* Wsm   = (const float*)d_in[8];
    const float* bs    = (const float*)d_in[9];
    const float* gamma = (const float*)d_in[10];
    const float* beta  = (const float*)d_in[11];
    const float* W1    = (const float*)d_in[12];
    const float* b1    = (const float*)d_in[13];
    const float* W2    = (const float*)d_in[14];
    const float* b2    = (const float*)d_in[15];
    const float* Wo    = (const float*)d_in[16];
    const float* bo    = (const float*)d_in[17];
    float* out = (float*)d_out;

    const int N = in_sizes[0]/16;
    const int E = in_sizes[1]/2;
    const int G = out_size;

    const int* srcI = eidx;
    const int* dstI = eidx + E;

    char* p = (char*)d_ws;
    auto alloc = [&](size_t bytes)->char*{ char* r = p; p += (bytes + 255) & ~255ull; return r; };
    float*  h      = (float*) alloc((size_t)N*H*4);
    float*  xn     = (float*) alloc((size_t)N*H*4);
    float*  TD     = (float*) alloc((size_t)N*2*H*4);
    float*  TS     = (float*) alloc((size_t)N*2*H*4);
    float*  ea_s   = (float*) alloc((size_t)E*EFD*4);
    int*    src_s  = (int*)   alloc((size_t)E*4);
    int*    rowptr = (int*)   alloc((size_t)(N+1)*4);
    int*    cursor = (int*)   alloc((size_t)N*4);   // also incl-scan temp
    int*    counts = (int*)   alloc((size_t)N*4);
    int*    bsums  = (int*)   alloc(256*4);
    double* sums   = (double*)alloc(2*H*8);
    float*  scsh   = (float*) alloc(2*H*4);

    const int thr = 256;
    hipMemsetAsync(counts, 0, (size_t)N*4, stream);
    hipMemsetAsync(sums, 0, 2*H*8, stream);
    embed_kernel<<<(N*H + thr-1)/thr, thr, 0, stream>>>(x, W_emb, b_emb, h, N);
    hist_kernel<<<(E + thr-1)/thr, thr, 0, stream>>>(dstI, counts, E);
    int nb = (N + 1023)/1024;
    scan1<<<nb, 1024, 0, stream>>>(counts, cursor, bsums, N);
    scan2<<<1, 64, 0, stream>>>(bsums, nb);
    scan3<<<nb, 1024, 0, stream>>>(cursor, counts, bsums, rowptr, cursor, N, E);
    scatter_kernel<<<(E + thr-1)/thr, thr, 0, stream>>>(srcI, dstI, eattr, cursor, src_s, ea_s, E);

    for (int l=0;l<NLAYER;l++){
        const float* Wf_l = Wf  + (size_t)l*ZDIM*H;
        const float* Ws_l = Wsm + (size_t)l*ZDIM*H;
        table_gemm<<<(N+31)/32, 256, 0, stream>>>(h, Wf_l, Ws_l, bf + l*H, bs + l*H, TD, TS, N);
        agg_kernel<<<(N+3)/4, 256, 0, stream>>>(TD, TS, rowptr, src_s, ea_s, Wf_l, Ws_l, h, xn, N);
        stats_kernel<<<256, 256, 0, stream>>>(xn, sums, N);
        finalize_bn<<<1, 128, 0, stream>>>(sums, gamma + l*H, beta + l*H, scsh, N);
        apply_bn<<<((N*H/4) + thr-1)/thr, thr, 0, stream>>>(xn, scsh, h, N*H/4);
    }

    pool_mlp_kernel<<<G, 128, 0, stream>>>(h, batch, W1, b1, W2, b2, Wo, bo, out, N);
}

// Round 4
// 1073.874 us; speedup vs baseline: 1.6192x; 1.2519x over previous
//
#include <hip/hip_runtime.h>
#include <hip/hip_bf16.h>

#define H 128
#define EFD 8
#define NLAYER 4
#define ZDIM (2*H+EFD)   // 264

typedef float f32x2 __attribute__((ext_vector_type(2)));
typedef float f32x4 __attribute__((ext_vector_type(4)));
typedef short s16x8 __attribute__((ext_vector_type(8)));

// packed fp32 fma with src0 broadcast from low/high half (VOP3P op_sel)
#define PKFMA_LO(acc, a, b) asm("v_pk_fma_f32 %0, %1, %2, %0 op_sel:[0,0,0] op_sel_hi:[0,1,1]" : "+v"(acc) : "v"(a), "v"(b))
#define PKFMA_HI(acc, a, b) asm("v_pk_fma_f32 %0, %1, %2, %0 op_sel:[1,0,0] op_sel_hi:[1,1,1]" : "+v"(acc) : "v"(a), "v"(b))

#define L2E 1.44269504088896340736f
#define LN2 0.69314718055994530942f

__device__ __forceinline__ unsigned short f2bf(float x){
    unsigned u = __float_as_uint(x);
    return (unsigned short)((u + 0x7FFFu + ((u>>16)&1u)) >> 16);
}

// h = relu(x @ W_emb + b_emb)   [N,16]@[16,128]
__global__ void embed_kernel(const float* __restrict__ x, const float* __restrict__ We,
                             const float* __restrict__ be, float* __restrict__ h, int N){
    int idx = blockIdx.x*blockDim.x + threadIdx.x;
    if (idx >= N*H) return;
    int n = idx >> 7, f = idx & 127;
    float a = be[f];
    #pragma unroll
    for (int k=0;k<16;k++) a = fmaf(x[n*16+k], We[k*H+f], a);
    h[idx] = fmaxf(a, 0.f);
}

__global__ void hist_kernel(const int* __restrict__ dstI, int* __restrict__ counts, int E){
    int e = blockIdx.x*blockDim.x + threadIdx.x;
    if (e < E) atomicAdd(&counts[dstI[e]], 1);
}

__global__ __launch_bounds__(1024) void scan1(const int* __restrict__ counts, int* __restrict__ incl,
                                              int* __restrict__ bsums, int N){
    __shared__ int lds[1024];
    int t = threadIdx.x;
    int i = blockIdx.x*1024 + t;
    int v = (i < N) ? counts[i] : 0;
    lds[t] = v;
    __syncthreads();
    for (int off=1; off<1024; off<<=1){
        int add = (t>=off) ? lds[t-off] : 0;
        __syncthreads();
        lds[t] += add;
        __syncthreads();
    }
    if (i < N) incl[i] = lds[t];
    if (t == 1023) bsums[blockIdx.x] = lds[1023];
}

__global__ void scan2(int* bsums, int nb){
    if (threadIdx.x == 0){
        int run = 0;
        for (int b=0;b<nb;b++){ int v = bsums[b]; bsums[b] = run; run += v; }
    }
}

__global__ __launch_bounds__(1024) void scan3(const int* incl, const int* __restrict__ counts,
                                              const int* __restrict__ bsums, int* __restrict__ rowptr,
                                              int* cursor, int N, int E){
    int i = blockIdx.x*1024 + threadIdx.x;
    if (i >= N) return;
    int ex = incl[i] - counts[i] + bsums[blockIdx.x];
    rowptr[i] = ex;
    cursor[i] = ex;
    if (i == N-1) rowptr[N] = E;
}

__global__ void scatter_kernel(const int* __restrict__ srcI, const int* __restrict__ dstI,
                               const float* __restrict__ eattr, int* __restrict__ cursor,
                               int* __restrict__ src_s, float* __restrict__ ea_s, int E){
    int e = blockIdx.x*blockDim.x + threadIdx.x;
    if (e >= E) return;
    int d = dstI[e];
    int pos = atomicAdd(&cursor[d], 1);
    src_s[pos] = srcI[e];
    const float4* s4 = (const float4*)(eattr + (size_t)e*EFD);
    float4* o4 = (float4*)(ea_s + (size_t)pos*EFD);
    o4[0] = s4[0]; o4[1] = s4[1];
}

// Pack node-part weights (rows 0..255 of Wf/Ws, all 4 layers) into per-lane MFMA B
// fragments, split hi/lo bf16. Index: idx = ((layer*4 + w)*4 + ks)*8*64 + ct*64 + lane.
// B frag element e: W[ks*32 + (lane>>4)*8 + e][w*128 + ct*16 + (lane&15)] of the
// virtual [128,512] Wcat = [Fd(Wf,k)|Sd(Ws,k)|Fs(Wf,128+k)|Ss(Ws,128+k)].
__global__ __launch_bounds__(256) void wpack_kernel(const float* __restrict__ Wf, const float* __restrict__ Ws,
        s16x8* __restrict__ bhi, s16x8* __restrict__ blo){
    int idx = blockIdx.x*256 + threadIdx.x;   // 32768 total
    int l = idx & 63, ct = (idx>>6)&7, ks = (idx>>9)&3, w = (idx>>11)&3, layer = idx>>13;
    int cp = w*128 + ct*16 + (l&15);
    int k0 = ks*32 + ((l>>4)<<3);
    const float* WfL = Wf + (size_t)layer*ZDIM*H;
    const float* WsL = Ws + (size_t)layer*ZDIM*H;
    int colIn = cp & 127;
    int sel = cp >> 7;
    const float* Wm = (sel & 1) ? WsL : WfL;
    int krow = (sel >> 1) ? H : 0;
    s16x8 vh, vl;
    #pragma unroll
    for (int e=0;e<8;e++){
        float v = Wm[(size_t)(krow + k0 + e)*H + colIn];
        unsigned short hb = f2bf(v);
        float rem = v - __uint_as_float(((unsigned)hb)<<16);
        vh[e] = (short)hb;
        vl[e] = (short)f2bf(rem);
    }
    bhi[idx] = vh;
    blo[idx] = vl;
}

// [N,128] @ [128,512] via bf16 MFMA with 3-term hi/lo split (~fp32 accuracy).
// Block: 32 nodes, 4 waves; wave w owns output cols [128w,128w+128).
// TD[n]=[Fd|Sd]+bias, TS[n]=[Fs|Ss]; everything pre-scaled by log2(e) for exp2-domain gates.
__global__ __launch_bounds__(256, 2) void table_mfma(
        const float* __restrict__ h, const s16x8* __restrict__ bhi, const s16x8* __restrict__ blo,
        const float* __restrict__ bf_l, const float* __restrict__ bs_l,
        float* __restrict__ TD, float* __restrict__ TS, int N, int layer){
    __shared__ __align__(16) short amat[2][32*136];   // hi/lo, 272B row pitch (2-way bank alias = free)
    const int t = threadIdx.x;
    const int n0 = blockIdx.x*32;
    {
        const int row = t >> 3, kb = (t & 7)*16;
        const int gn = n0 + row;
        const float* src = h + (size_t)gn*H + kb;
        float vv[16];
        #pragma unroll
        for (int q=0;q<16;q+=4){
            float4 x4 = (gn < N) ? *(const float4*)(src + q) : make_float4(0.f,0.f,0.f,0.f);
            vv[q]=x4.x; vv[q+1]=x4.y; vv[q+2]=x4.z; vv[q+3]=x4.w;
        }
        s16x8 hv[2], lv[2];
        #pragma unroll
        for (int q=0;q<16;q++){
            unsigned short hb = f2bf(vv[q]);
            float rem = vv[q] - __uint_as_float(((unsigned)hb)<<16);
            hv[q>>3][q&7] = (short)hb;
            lv[q>>3][q&7] = (short)f2bf(rem);
        }
        short* dh = &amat[0][row*136 + kb];
        short* dl = &amat[1][row*136 + kb];
        *(s16x8*)dh = hv[0]; *(s16x8*)(dh+8) = hv[1];
        *(s16x8*)dl = lv[0]; *(s16x8*)(dl+8) = lv[1];
    }
    __syncthreads();
    const int lane = t & 63, w = t >> 6;
    const int rbase = lane & 15, kg = lane >> 4;
    f32x4 acc[2][8];
    #pragma unroll
    for (int rt=0;rt<2;rt++)
        #pragma unroll
        for (int ct=0;ct<8;ct++){ acc[rt][ct][0]=0.f; acc[rt][ct][1]=0.f; acc[rt][ct][2]=0.f; acc[rt][ct][3]=0.f; }
    const size_t bbase = ((size_t)layer*4 + w)*2048;
    #pragma unroll
    for (int ks=0;ks<4;ks++){
        s16x8 bh[8], bl[8];
        #pragma unroll
        for (int ct=0;ct<8;ct++){
            bh[ct] = bhi[bbase + ks*512 + ct*64 + lane];
            bl[ct] = blo[bbase + ks*512 + ct*64 + lane];
        }
        s16x8 ah[2], al[2];
        #pragma unroll
        for (int rt=0;rt<2;rt++){
            const int ao = (rbase + 16*rt)*136 + ks*32 + kg*8;
            ah[rt] = *(const s16x8*)&amat[0][ao];
            al[rt] = *(const s16x8*)&amat[1][ao];
        }
        #pragma unroll
        for (int ct=0;ct<8;ct++)
            #pragma unroll
            for (int rt=0;rt<2;rt++){
                acc[rt][ct] = __builtin_amdgcn_mfma_f32_16x16x32_bf16(ah[rt], bh[ct], acc[rt][ct], 0, 0, 0);
                acc[rt][ct] = __builtin_amdgcn_mfma_f32_16x16x32_bf16(ah[rt], bl[ct], acc[rt][ct], 0, 0, 0);
                acc[rt][ct] = __builtin_amdgcn_mfma_f32_16x16x32_bf16(al[rt], bh[ct], acc[rt][ct], 0, 0, 0);
            }
    }
    float* outb = (w < 2) ? TD : TS;
    const int colbase = (w & 1)*128;
    const float* bias = (w == 0) ? bf_l : (w == 1) ? bs_l : nullptr;
    #pragma unroll
    for (int ct=0;ct<8;ct++){
        const int c_local = ct*16 + rbase;
        const float bv = bias ? bias[c_local]*L2E : 0.f;
        #pragma unroll
        for (int rt=0;rt<2;rt++){
            const int nrow0 = n0 + 16*rt + kg*4;
            #pragma unroll
            for (int r=0;r<4;r++){
                const int nd = nrow0 + r;
                if (nd < N) outb[(size_t)nd*256 + colbase + c_local] = fmaf(acc[rt][ct][r], L2E, bv);
            }
        }
    }
}

// One wave per node; weights pinned in VGPRs; packed fp32 fma; exp2-domain gates;
// one-edge-ahead software pipeline; SGPR-base gathers.
__global__ __launch_bounds__(256, 4) void agg_kernel(
        const float* __restrict__ TD, const float* __restrict__ TS,
        const int* __restrict__ rowptr, const int* __restrict__ src_s, const float* __restrict__ ea_s,
        const float* __restrict__ Wf_l, const float* __restrict__ Ws_l,
        const float* __restrict__ h, float* __restrict__ xn, int N){
    __shared__ float wE[2048];   // [8][128] Wf edge rows, then [8][128] Ws edge rows (scaled by log2e)
    const int t = threadIdx.x;
    {
        const float4* a = (const float4*)(Wf_l + 2*H*H);
        const float4* b = (const float4*)(Ws_l + 2*H*H);
        float4 va = a[t], vb = b[t];
        va.x*=L2E; va.y*=L2E; va.z*=L2E; va.w*=L2E;
        vb.x*=L2E; vb.y*=L2E; vb.z*=L2E; vb.w*=L2E;
        ((float4*)wE)[t] = va;
        ((float4*)wE)[256 + t] = vb;
    }
    __syncthreads();
    const int k = t & 63;
    const int i = blockIdx.x*4 + (t >> 6);
    if (i >= N) return;
    f32x2 wef2[8], wes2[8];
    #pragma unroll
    for (int r=0;r<8;r++){
        wef2[r] = *(const f32x2*)&wE[r*128 + 2*k];
        wes2[r] = *(const f32x2*)&wE[1024 + r*128 + 2*k];
    }
    #pragma unroll
    for (int r=0;r<8;r++) asm volatile("" : "+v"(wef2[r]), "+v"(wes2[r]));
    const f32x2* td = (const f32x2*)(TD + ((size_t)i << 8));
    f32x2 fd2 = td[k], sd2 = td[64+k];
    f32x2 acc = {0.f, 0.f};
    const int e0 = __builtin_amdgcn_readfirstlane(rowptr[i]);
    const int e1 = __builtin_amdgcn_readfirstlane(rowptr[i+1]);
    int j = __builtin_amdgcn_readfirstlane(src_s[e0]);
    const float* eb = ea_s + (size_t)e0*EFD;
    f32x2 ea0 = *(const f32x2*)(eb);
    f32x2 ea1 = *(const f32x2*)(eb+2);
    f32x2 ea2 = *(const f32x2*)(eb+4);
    f32x2 ea3 = *(const f32x2*)(eb+6);
    for (int e = e0; e < e1; ++e){
        const float* tsrow = TS + ((size_t)(unsigned)j << 8);
        f32x2 fs2 = *(const f32x2*)(tsrow + 2*k);
        f32x2 ss2 = *(const f32x2*)(tsrow + 128 + 2*k);
        const int en = (e+1 < e1) ? (e+1) : e;
        const int jn = __builtin_amdgcn_readfirstlane(src_s[en]);
        const float* ebn = ea_s + (size_t)en*EFD;
        f32x2 na0 = *(const f32x2*)(ebn);
        f32x2 na1 = *(const f32x2*)(ebn+2);
        f32x2 na2 = *(const f32x2*)(ebn+4);
        f32x2 na3 = *(const f32x2*)(ebn+6);
        f32x2 ef = fd2, es = sd2;
        PKFMA_LO(ef, ea0, wef2[0]); PKFMA_HI(ef, ea0, wef2[1]);
        PKFMA_LO(ef, ea1, wef2[2]); PKFMA_HI(ef, ea1, wef2[3]);
        PKFMA_LO(ef, ea2, wef2[4]); PKFMA_HI(ef, ea2, wef2[5]);
        PKFMA_LO(ef, ea3, wef2[6]); PKFMA_HI(ef, ea3, wef2[7]);
        PKFMA_LO(es, ea0, wes2[0]); PKFMA_HI(es, ea0, wes2[1]);
        PKFMA_LO(es, ea1, wes2[2]); PKFMA_HI(es, ea1, wes2[3]);
        PKFMA_LO(es, ea2, wes2[4]); PKFMA_HI(es, ea2, wes2[5]);
        PKFMA_LO(es, ea3, wes2[6]); PKFMA_HI(es, ea3, wes2[7]);
        f32x2 g = ef + fs2;
        f32x2 p = es + ss2;
        float sx = __builtin_amdgcn_rcpf(1.0f + __builtin_amdgcn_exp2f(-g.x));
        float sy = __builtin_amdgcn_rcpf(1.0f + __builtin_amdgcn_exp2f(-g.y));
        float tx = fmaxf(p.x, 0.f) + __builtin_amdgcn_logf(1.0f + __builtin_amdgcn_exp2f(-fabsf(p.x)));
        float ty = fmaxf(p.y, 0.f) + __builtin_amdgcn_logf(1.0f + __builtin_amdgcn_exp2f(-fabsf(p.y)));
        acc.x = fmaf(sx*tx, LN2, acc.x);
        acc.y = fmaf(sy*ty, LN2, acc.y);
        j = jn; ea0 = na0; ea1 = na1; ea2 = na2; ea3 = na3;
    }
    f32x2 hv = *(const f32x2*)(h + ((size_t)i << 7) + 2*k);
    f32x2 o = acc + hv;
    *(f32x2*)(xn + ((size_t)i << 7) + 2*k) = o;
}

__global__ __launch_bounds__(256) void stats_kernel(const float* __restrict__ xn, double* __restrict__ sums, int N){
    __shared__ double l1[128], l2[128];
    const int f = threadIdx.x & 127;
    const int half = threadIdx.x >> 7;
    const int nb = gridDim.x;
    const int per = (N + nb - 1)/nb;
    const int r0 = blockIdx.x*per;
    const int r1 = min(N, r0+per);
    double s = 0.0, s2 = 0.0;
    for (int r=r0+half; r<r1; r+=2){
        float v = xn[(size_t)r*H + f];
        s += v; s2 += (double)v*(double)v;
    }
    if (half == 1){ l1[f] = s; l2[f] = s2; }
    __syncthreads();
    if (half == 0){
        s += l1[f]; s2 += l2[f];
        atomicAdd(&sums[f], s);
        atomicAdd(&sums[H+f], s2);
    }
}

__global__ void finalize_bn(double* __restrict__ sums, const float* __restrict__ gamma_l,
                            const float* __restrict__ beta_l, float* __restrict__ scsh, int N){
    int f = threadIdx.x;
    if (f >= H) return;
    double mu = sums[f]/(double)N;
    double var = sums[H+f]/(double)N - mu*mu;
    if (var < 0.0) var = 0.0;
    float sc = (float)((double)gamma_l[f] / sqrt(var + 1e-5));
    scsh[f]   = sc;
    scsh[H+f] = (float)((double)beta_l[f] - mu*(double)sc);
    sums[f] = 0.0;       // reset for next layer
    sums[H+f] = 0.0;
}

__global__ __launch_bounds__(256) void apply_bn(const float* __restrict__ xn, const float* __restrict__ scsh,
                                                float* __restrict__ h, int total4){
    int idx = blockIdx.x*blockDim.x + threadIdx.x;
    if (idx >= total4) return;
    int f = (idx*4) & (H-1);
    float4 v  = *(const float4*)(xn + (size_t)idx*4);
    float4 hh = *(const float4*)(h  + (size_t)idx*4);
    float4 sc = *(const float4*)(scsh + f);
    float4 sh = *(const float4*)(scsh + H + f);
    hh.x += fmaxf(fmaf(v.x, sc.x, sh.x), 0.f);
    hh.y += fmaxf(fmaf(v.y, sc.y, sh.y), 0.f);
    hh.z += fmaxf(fmaf(v.z, sc.z, sh.z), 0.f);
    hh.w += fmaxf(fmaf(v.w, sc.w, sh.w), 0.f);
    *(float4*)(h + (size_t)idx*4) = hh;
}

// One block per graph: binary-search sorted batch for the segment, mean-pool, then MLP.
__global__ __launch_bounds__(128) void pool_mlp_kernel(const float* __restrict__ h, const int* __restrict__ batch,
        const float* __restrict__ W1, const float* __restrict__ b1,
        const float* __restrict__ W2, const float* __restrict__ b2,
        const float* __restrict__ Wo, const float* __restrict__ bo,
        float* __restrict__ out, int N){
    __shared__ float row[128];
    __shared__ float g1[64];
    __shared__ float g2[32];
    const int g = blockIdx.x;
    const int t = threadIdx.x;
    int lo = 0, hi = N;
    while (lo < hi){ int m = (lo+hi)>>1; if (batch[m] < g) lo = m+1; else hi = m; }
    const int s0 = lo;
    hi = N;
    while (lo < hi){ int m = (lo+hi)>>1; if (batch[m] < g+1) lo = m+1; else hi = m; }
    const int s1 = lo;
    float acc = 0.f;
    for (int r = s0; r < s1; ++r) acc += h[(size_t)r*H + t];
    const float inv = 1.0f/fmaxf((float)(s1-s0), 1.0f);
    row[t] = acc*inv;
    __syncthreads();
    if (t < 64){
        float a = b1[t];
        #pragma unroll 4
        for (int i2=0;i2<128;i2++) a = fmaf(row[i2], W1[i2*64+t], a);
        g1[t] = fmaxf(a, 0.f);
    }
    __syncthreads();
    if (t < 32){
        float b = b2[t];
        #pragma unroll 4
        for (int i2=0;i2<64;i2++) b = fmaf(g1[i2], W2[i2*32+t], b);
        g2[t] = fmaxf(b, 0.f);
    }
    __syncthreads();
    if (t < 64){
        float p = (t < 32) ? g2[t]*Wo[t] : 0.f;
        for (int off=32; off>0; off>>=1) p += __shfl_down(p, off);
        if (t == 0) out[g] = p + bo[0];
    }
}

extern "C" void kernel_launch(void* const* d_in, const int* in_sizes, int n_in,
                              void* d_out, int out_size, void* d_ws, size_t ws_size,
                              hipStream_t stream){
    const float* x     = (const float*)d_in[0];
    const int*   eidx  = (const int*)d_in[1];
    const float* eattr = (const float*)d_in[2];
    const int*   batch = (const int*)d_in[3];
    const float* W_emb = (const float*)d_in[4];
    const float* b_emb = (const float*)d_in[5];
    const float* Wf    = (const float*)d_in[6];
    const float* bf    = (const float*)d_in[7];
    const float* Wsm   = (const float*)d_in[8];
    const float* bs    = (const float*)d_in[9];
    const float* gamma = (const float*)d_in[10];
    const float* beta  = (const float*)d_in[11];
    const float* W1    = (const float*)d_in[12];
    const float* b1    = (const float*)d_in[13];
    const float* W2    = (const float*)d_in[14];
    const float* b2    = (const float*)d_in[15];
    const float* Wo    = (const float*)d_in[16];
    const float* bo    = (const float*)d_in[17];
    float* out = (float*)d_out;

    const int N = in_sizes[0]/16;
    const int E = in_sizes[1]/2;
    const int G = out_size;

    const int* srcI = eidx;
    const int* dstI = eidx + E;

    char* p = (char*)d_ws;
    auto alloc = [&](size_t bytes)->char*{ char* r = p; p += (bytes + 255) & ~255ull; return r; };
    float*  h      = (float*) alloc((size_t)N*H*4);
    float*  xn     = (float*) alloc((size_t)N*H*4);
    float*  TD     = (float*) alloc((size_t)N*2*H*4);
    float*  TS     = (float*) alloc((size_t)N*2*H*4);
    float*  ea_s   = (float*) alloc((size_t)E*EFD*4);
    int*    src_s  = (int*)   alloc((size_t)E*4);
    int*    rowptr = (int*)   alloc((size_t)(N+1)*4);
    int*    cursor = (int*)   alloc((size_t)N*4);   // also incl-scan temp
    int*    counts = (int*)   alloc((size_t)N*4);
    int*    bsums  = (int*)   alloc(256*4);
    double* sums   = (double*)alloc(2*H*8);
    float*  scsh   = (float*) alloc(2*H*4);
    s16x8*  bhi    = (s16x8*) alloc((size_t)NLAYER*8192*16);
    s16x8*  blo    = (s16x8*) alloc((size_t)NLAYER*8192*16);

    const int thr = 256;
    hipMemsetAsync(counts, 0, (size_t)N*4, stream);
    hipMemsetAsync(sums, 0, 2*H*8, stream);
    embed_kernel<<<(N*H + thr-1)/thr, thr, 0, stream>>>(x, W_emb, b_emb, h, N);
    hist_kernel<<<(E + thr-1)/thr, thr, 0, stream>>>(dstI, counts, E);
    int nb = (N + 1023)/1024;
    scan1<<<nb, 1024, 0, stream>>>(counts, cursor, bsums, N);
    scan2<<<1, 64, 0, stream>>>(bsums, nb);
    scan3<<<nb, 1024, 0, stream>>>(cursor, counts, bsums, rowptr, cursor, N, E);
    scatter_kernel<<<(E + thr-1)/thr, thr, 0, stream>>>(srcI, dstI, eattr, cursor, src_s, ea_s, E);
    wpack_kernel<<<128, 256, 0, stream>>>(Wf, Wsm, bhi, blo);

    for (int l=0;l<NLAYER;l++){
        const float* Wf_l = Wf  + (size_t)l*ZDIM*H;
        const float* Ws_l = Wsm + (size_t)l*ZDIM*H;
        table_mfma<<<(N+31)/32, 256, 0, stream>>>(h, bhi, blo, bf + l*H, bs + l*H, TD, TS, N, l);
        agg_kernel<<<(N+3)/4, 256, 0, stream>>>(TD, TS, rowptr, src_s, ea_s, Wf_l, Ws_l, h, xn, N);
        stats_kernel<<<256, 256, 0, stream>>>(xn, sums, N);
        finalize_bn<<<1, 128, 0, stream>>>(sums, gamma + l*H, beta + l*H, scsh, N);
        apply_bn<<<((N*H/4) + thr-1)/thr, thr, 0, stream>>>(xn, scsh, h, N*H/4);
    }

    pool_mlp_kernel<<<G, 128, 0, stream>>>(h, batch, W1, b1, W2, b2, Wo, bo, out, N);
}

// Round 5
// 935.536 us; speedup vs baseline: 1.8587x; 1.1479x over previous
//
#include <hip/hip_runtime.h>
#include <hip/hip_bf16.h>

#define H 128
#define EFD 8
#define NLAYER 4
#define ZDIM (2*H+EFD)   // 264

typedef float f32x2 __attribute__((ext_vector_type(2)));
typedef float f32x4 __attribute__((ext_vector_type(4)));
typedef short s16x8 __attribute__((ext_vector_type(8)));
typedef _Float16 f16x4 __attribute__((ext_vector_type(4)));

// packed fp32 fma with src0 broadcast from low/high half (VOP3P op_sel)
#define PKFMA_LO(acc, a, b) asm("v_pk_fma_f32 %0, %1, %2, %0 op_sel:[0,0,0] op_sel_hi:[0,1,1]" : "+v"(acc) : "v"(a), "v"(b))
#define PKFMA_HI(acc, a, b) asm("v_pk_fma_f32 %0, %1, %2, %0 op_sel:[1,0,0] op_sel_hi:[1,1,1]" : "+v"(acc) : "v"(a), "v"(b))
#define PKFMA_LO_INIT(dst, a, b, c) asm("v_pk_fma_f32 %0, %1, %2, %3 op_sel:[0,0,0] op_sel_hi:[0,1,1]" : "=v"(dst) : "v"(a), "v"(b), "v"(c))

#define L2E 1.44269504088896340736f
#define LN2 0.69314718055994530942f

__device__ __forceinline__ unsigned short f2bf(float x){
    unsigned u = __float_as_uint(x);
    return (unsigned short)((u + 0x7FFFu + ((u>>16)&1u)) >> 16);
}

// h = relu(x @ W_emb + b_emb)   [N,16]@[16,128]
__global__ void embed_kernel(const float* __restrict__ x, const float* __restrict__ We,
                             const float* __restrict__ be, float* __restrict__ h, int N){
    int idx = blockIdx.x*blockDim.x + threadIdx.x;
    if (idx >= N*H) return;
    int n = idx >> 7, f = idx & 127;
    float a = be[f];
    #pragma unroll
    for (int k=0;k<16;k++) a = fmaf(x[n*16+k], We[k*H+f], a);
    h[idx] = fmaxf(a, 0.f);
}

__global__ void hist_kernel(const int* __restrict__ dstI, int* __restrict__ counts, int E){
    int e = blockIdx.x*blockDim.x + threadIdx.x;
    if (e < E) atomicAdd(&counts[dstI[e]], 1);
}

__global__ __launch_bounds__(1024) void scan1(const int* __restrict__ counts, int* __restrict__ incl,
                                              int* __restrict__ bsums, int N){
    __shared__ int lds[1024];
    int t = threadIdx.x;
    int i = blockIdx.x*1024 + t;
    int v = (i < N) ? counts[i] : 0;
    lds[t] = v;
    __syncthreads();
    for (int off=1; off<1024; off<<=1){
        int add = (t>=off) ? lds[t-off] : 0;
        __syncthreads();
        lds[t] += add;
        __syncthreads();
    }
    if (i < N) incl[i] = lds[t];
    if (t == 1023) bsums[blockIdx.x] = lds[1023];
}

__global__ void scan2(int* bsums, int nb){
    if (threadIdx.x == 0){
        int run = 0;
        for (int b=0;b<nb;b++){ int v = bsums[b]; bsums[b] = run; run += v; }
    }
}

__global__ __launch_bounds__(1024) void scan3(const int* incl, const int* __restrict__ counts,
                                              const int* __restrict__ bsums, int* __restrict__ rowptr,
                                              int* cursor, int N, int E){
    int i = blockIdx.x*1024 + threadIdx.x;
    if (i >= N) return;
    int ex = incl[i] - counts[i] + bsums[blockIdx.x];
    rowptr[i] = ex;
    cursor[i] = ex;
    if (i == N-1) rowptr[N] = E;
}

__global__ void scatter_kernel(const int* __restrict__ srcI, const int* __restrict__ dstI,
                               const float* __restrict__ eattr, int* __restrict__ cursor,
                               int* __restrict__ src_s, float* __restrict__ ea_s, int E){
    int e = blockIdx.x*blockDim.x + threadIdx.x;
    if (e >= E) return;
    int d = dstI[e];
    int pos = atomicAdd(&cursor[d], 1);
    src_s[pos] = srcI[e];
    const float4* s4 = (const float4*)(eattr + (size_t)e*EFD);
    float4* o4 = (float4*)(ea_s + (size_t)pos*EFD);
    o4[0] = s4[0]; o4[1] = s4[1];
}

// Pack node-part weights (rows 0..255 of Wf/Ws, all 4 layers) into per-lane MFMA B
// fragments, split hi/lo bf16. Index: idx = ((layer*4 + w)*4 + ks)*8*64 + ct*64 + lane.
__global__ __launch_bounds__(256) void wpack_kernel(const float* __restrict__ Wf, const float* __restrict__ Ws,
        s16x8* __restrict__ bhi, s16x8* __restrict__ blo){
    int idx = blockIdx.x*256 + threadIdx.x;   // 32768 total
    int l = idx & 63, ct = (idx>>6)&7, ks = (idx>>9)&3, w = (idx>>11)&3, layer = idx>>13;
    int cp = w*128 + ct*16 + (l&15);
    int k0 = ks*32 + ((l>>4)<<3);
    const float* WfL = Wf + (size_t)layer*ZDIM*H;
    const float* WsL = Ws + (size_t)layer*ZDIM*H;
    int colIn = cp & 127;
    int sel = cp >> 7;
    const float* Wm = (sel & 1) ? WsL : WfL;
    int krow = (sel >> 1) ? H : 0;
    s16x8 vh, vl;
    #pragma unroll
    for (int e=0;e<8;e++){
        float v = Wm[(size_t)(krow + k0 + e)*H + colIn];
        unsigned short hb = f2bf(v);
        float rem = v - __uint_as_float(((unsigned)hb)<<16);
        vh[e] = (short)hb;
        vl[e] = (short)f2bf(rem);
    }
    bhi[idx] = vh;
    blo[idx] = vl;
}

// [N,128] @ [128,512] via bf16 MFMA with 3-term hi/lo split (~fp32 accuracy).
// Block: 32 nodes, 4 waves; wave w owns output cols [128w,128w+128).
// w<2 -> TD fp32 [Fd|Sd]+bias; w>=2 -> TS16 fp16 interleaved (F2k,F2k+1,S2k,S2k+1 per k).
// Everything pre-scaled by log2(e) for exp2-domain gates.
__global__ __launch_bounds__(256, 2) void table_mfma(
        const float* __restrict__ h, const s16x8* __restrict__ bhi, const s16x8* __restrict__ blo,
        const float* __restrict__ bf_l, const float* __restrict__ bs_l,
        float* __restrict__ TD, _Float16* __restrict__ TS16, int N, int layer){
    __shared__ __align__(16) short amat[2][32*136];   // hi/lo, 272B row pitch (2-way bank alias = free)
    const int t = threadIdx.x;
    const int n0 = blockIdx.x*32;
    {
        const int row = t >> 3, kb = (t & 7)*16;
        const int gn = n0 + row;
        const float* src = h + (size_t)gn*H + kb;
        float vv[16];
        #pragma unroll
        for (int q=0;q<16;q+=4){
            float4 x4 = (gn < N) ? *(const float4*)(src + q) : make_float4(0.f,0.f,0.f,0.f);
            vv[q]=x4.x; vv[q+1]=x4.y; vv[q+2]=x4.z; vv[q+3]=x4.w;
        }
        s16x8 hv[2], lv[2];
        #pragma unroll
        for (int q=0;q<16;q++){
            unsigned short hb = f2bf(vv[q]);
            float rem = vv[q] - __uint_as_float(((unsigned)hb)<<16);
            hv[q>>3][q&7] = (short)hb;
            lv[q>>3][q&7] = (short)f2bf(rem);
        }
        short* dh = &amat[0][row*136 + kb];
        short* dl = &amat[1][row*136 + kb];
        *(s16x8*)dh = hv[0]; *(s16x8*)(dh+8) = hv[1];
        *(s16x8*)dl = lv[0]; *(s16x8*)(dl+8) = lv[1];
    }
    __syncthreads();
    const int lane = t & 63, w = t >> 6;
    const int rbase = lane & 15, kg = lane >> 4;
    f32x4 acc[2][8];
    #pragma unroll
    for (int rt=0;rt<2;rt++)
        #pragma unroll
        for (int ct=0;ct<8;ct++){ acc[rt][ct][0]=0.f; acc[rt][ct][1]=0.f; acc[rt][ct][2]=0.f; acc[rt][ct][3]=0.f; }
    const size_t bbase = ((size_t)layer*4 + w)*2048;
    #pragma unroll
    for (int ks=0;ks<4;ks++){
        s16x8 bh[8], bl[8];
        #pragma unroll
        for (int ct=0;ct<8;ct++){
            bh[ct] = bhi[bbase + ks*512 + ct*64 + lane];
            bl[ct] = blo[bbase + ks*512 + ct*64 + lane];
        }
        s16x8 ah[2], al[2];
        #pragma unroll
        for (int rt=0;rt<2;rt++){
            const int ao = (rbase + 16*rt)*136 + ks*32 + kg*8;
            ah[rt] = *(const s16x8*)&amat[0][ao];
            al[rt] = *(const s16x8*)&amat[1][ao];
        }
        #pragma unroll
        for (int ct=0;ct<8;ct++)
            #pragma unroll
            for (int rt=0;rt<2;rt++){
                acc[rt][ct] = __builtin_amdgcn_mfma_f32_16x16x32_bf16(ah[rt], bh[ct], acc[rt][ct], 0, 0, 0);
                acc[rt][ct] = __builtin_amdgcn_mfma_f32_16x16x32_bf16(ah[rt], bl[ct], acc[rt][ct], 0, 0, 0);
                acc[rt][ct] = __builtin_amdgcn_mfma_f32_16x16x32_bf16(al[rt], bh[ct], acc[rt][ct], 0, 0, 0);
            }
    }
    if (w < 2){
        float* outb = TD;
        const int colbase = (w & 1)*128;
        const float* bias = (w == 0) ? bf_l : bs_l;
        #pragma unroll
        for (int ct=0;ct<8;ct++){
            const int c_local = ct*16 + rbase;
            const float bv = bias[c_local]*L2E;
            #pragma unroll
            for (int rt=0;rt<2;rt++){
                const int nrow0 = n0 + 16*rt + kg*4;
                #pragma unroll
                for (int r=0;r<4;r++){
                    const int nd = nrow0 + r;
                    if (nd < N) outb[(size_t)nd*256 + colbase + c_local] = fmaf(acc[rt][ct][r], L2E, bv);
                }
            }
        }
    } else {
        const int slot = (w & 1) << 1;   // w==2 -> F slots, w==3 -> S slots
        #pragma unroll
        for (int ct=0;ct<8;ct++){
            const int c_local = ct*16 + rbase;
            const int off = (c_local >> 1)*4 + slot + (c_local & 1);
            #pragma unroll
            for (int rt=0;rt<2;rt++){
                const int nrow0 = n0 + 16*rt + kg*4;
                #pragma unroll
                for (int r=0;r<4;r++){
                    const int nd = nrow0 + r;
                    if (nd < N) TS16[(size_t)nd*256 + off] = (_Float16)(acc[rt][ct][r]*L2E);
                }
            }
        }
    }
}

// One wave per node; weights pinned in VGPRs; packed fp32 fma; exp2-domain gates.
// Src table gathered as fp16 interleaved: one 8B load per lane per edge.
__global__ __launch_bounds__(256, 4) void agg_kernel(
        const float* __restrict__ TD, const _Float16* __restrict__ TS16,
        const int* __restrict__ rowptr, const int* __restrict__ src_s, const float* __restrict__ ea_s,
        const float* __restrict__ Wf_l, const float* __restrict__ Ws_l,
        const float* __restrict__ h, float* __restrict__ xn, int N){
    __shared__ float wE[2048];   // [8][128] Wf edge rows, then [8][128] Ws edge rows (scaled by log2e)
    const int t = threadIdx.x;
    {
        const float4* a = (const float4*)(Wf_l + 2*H*H);
        const float4* b = (const float4*)(Ws_l + 2*H*H);
        float4 va = a[t], vb = b[t];
        va.x*=L2E; va.y*=L2E; va.z*=L2E; va.w*=L2E;
        vb.x*=L2E; vb.y*=L2E; vb.z*=L2E; vb.w*=L2E;
        ((float4*)wE)[t] = va;
        ((float4*)wE)[256 + t] = vb;
    }
    __syncthreads();
    const int k = t & 63;
    const int i = blockIdx.x*4 + (t >> 6);
    if (i >= N) return;
    f32x2 wef2[8], wes2[8];
    #pragma unroll
    for (int r=0;r<8;r++){
        wef2[r] = *(const f32x2*)&wE[r*128 + 2*k];
        wes2[r] = *(const f32x2*)&wE[1024 + r*128 + 2*k];
    }
    #pragma unroll
    for (int r=0;r<8;r++) asm volatile("" : "+v"(wef2[r]), "+v"(wes2[r]));
    const f32x2* td = (const f32x2*)(TD + ((size_t)i << 8));
    f32x2 fd2 = td[k], sd2 = td[64+k];
    f32x2 acc = {0.f, 0.f};
    const int e0 = __builtin_amdgcn_readfirstlane(rowptr[i]);
    const int e1 = __builtin_amdgcn_readfirstlane(rowptr[i+1]);
    int j = (e0 < e1) ? __builtin_amdgcn_readfirstlane(src_s[e0]) : 0;
    for (int e = e0; e < e1; ++e){
        const _Float16* tsrow = TS16 + ((size_t)(unsigned)j << 8);
        f16x4 tv = *(const f16x4*)(tsrow + 4*k);
        const int en = (e+1 < e1) ? (e+1) : e;
        const int jn = __builtin_amdgcn_readfirstlane(src_s[en]);
        const float* eb = ea_s + (size_t)e*EFD;
        f32x4 eaA = *(const f32x4*)(eb);
        f32x4 eaB = *(const f32x4*)(eb+4);
        f32x2 ea0 = __builtin_shufflevector(eaA, eaA, 0, 1);
        f32x2 ea1 = __builtin_shufflevector(eaA, eaA, 2, 3);
        f32x2 ea2 = __builtin_shufflevector(eaB, eaB, 0, 1);
        f32x2 ea3 = __builtin_shufflevector(eaB, eaB, 2, 3);
        f32x2 ef, es;
        PKFMA_LO_INIT(ef, ea0, wef2[0], fd2);
        PKFMA_HI(ef, ea0, wef2[1]);
        PKFMA_LO(ef, ea1, wef2[2]); PKFMA_HI(ef, ea1, wef2[3]);
        PKFMA_LO(ef, ea2, wef2[4]); PKFMA_HI(ef, ea2, wef2[5]);
        PKFMA_LO(ef, ea3, wef2[6]); PKFMA_HI(ef, ea3, wef2[7]);
        PKFMA_LO_INIT(es, ea0, wes2[0], sd2);
        PKFMA_HI(es, ea0, wes2[1]);
        PKFMA_LO(es, ea1, wes2[2]); PKFMA_HI(es, ea1, wes2[3]);
        PKFMA_LO(es, ea2, wes2[4]); PKFMA_HI(es, ea2, wes2[5]);
        PKFMA_LO(es, ea3, wes2[6]); PKFMA_HI(es, ea3, wes2[7]);
        f32x2 fs2 = {(float)tv[0], (float)tv[1]};
        f32x2 ss2 = {(float)tv[2], (float)tv[3]};
        f32x2 g = ef + fs2;
        f32x2 p = es + ss2;
        float sx = __builtin_amdgcn_rcpf(1.0f + __builtin_amdgcn_exp2f(-g.x));
        float sy = __builtin_amdgcn_rcpf(1.0f + __builtin_amdgcn_exp2f(-g.y));
        float tx = fmaxf(p.x, 0.f) + __builtin_amdgcn_logf(1.0f + __builtin_amdgcn_exp2f(-fabsf(p.x)));
        float ty = fmaxf(p.y, 0.f) + __builtin_amdgcn_logf(1.0f + __builtin_amdgcn_exp2f(-fabsf(p.y)));
        acc.x = fmaf(sx*tx, LN2, acc.x);
        acc.y = fmaf(sy*ty, LN2, acc.y);
        j = jn;
    }
    f32x2 hv = *(const f32x2*)(h + ((size_t)i << 7) + 2*k);
    f32x2 o = acc + hv;
    *(f32x2*)(xn + ((size_t)i << 7) + 2*k) = o;
}

__global__ __launch_bounds__(256) void stats_kernel(const float* __restrict__ xn, double* __restrict__ sums, int N){
    __shared__ double l1[128], l2[128];
    const int f = threadIdx.x & 127;
    const int half = threadIdx.x >> 7;
    const int nb = gridDim.x;
    const int per = (N + nb - 1)/nb;
    const int r0 = blockIdx.x*per;
    const int r1 = min(N, r0+per);
    double s = 0.0, s2 = 0.0;
    for (int r=r0+half; r<r1; r+=2){
        float v = xn[(size_t)r*H + f];
        s += v; s2 += (double)v*(double)v;
    }
    if (half == 1){ l1[f] = s; l2[f] = s2; }
    __syncthreads();
    if (half == 0){
        s += l1[f]; s2 += l2[f];
        atomicAdd(&sums[f], s);
        atomicAdd(&sums[H+f], s2);
    }
}

__global__ void finalize_bn(double* __restrict__ sums, const float* __restrict__ gamma_l,
                            const float* __restrict__ beta_l, float* __restrict__ scsh, int N){
    int f = threadIdx.x;
    if (f >= H) return;
    double mu = sums[f]/(double)N;
    double var = sums[H+f]/(double)N - mu*mu;
    if (var < 0.0) var = 0.0;
    float sc = (float)((double)gamma_l[f] / sqrt(var + 1e-5));
    scsh[f]   = sc;
    scsh[H+f] = (float)((double)beta_l[f] - mu*(double)sc);
    sums[f] = 0.0;       // reset for next layer
    sums[H+f] = 0.0;
}

__global__ __launch_bounds__(256) void apply_bn(const float* __restrict__ xn, const float* __restrict__ scsh,
                                                float* __restrict__ h, int total4){
    int idx = blockIdx.x*blockDim.x + threadIdx.x;
    if (idx >= total4) return;
    int f = (idx*4) & (H-1);
    float4 v  = *(const float4*)(xn + (size_t)idx*4);
    float4 hh = *(const float4*)(h  + (size_t)idx*4);
    float4 sc = *(const float4*)(scsh + f);
    float4 sh = *(const float4*)(scsh + H + f);
    hh.x += fmaxf(fmaf(v.x, sc.x, sh.x), 0.f);
    hh.y += fmaxf(fmaf(v.y, sc.y, sh.y), 0.f);
    hh.z += fmaxf(fmaf(v.z, sc.z, sh.z), 0.f);
    hh.w += fmaxf(fmaf(v.w, sc.w, sh.w), 0.f);
    *(float4*)(h + (size_t)idx*4) = hh;
}

// One block per graph: binary-search sorted batch for the segment, mean-pool, then MLP.
__global__ __launch_bounds__(128) void pool_mlp_kernel(const float* __restrict__ h, const int* __restrict__ batch,
        const float* __restrict__ W1, const float* __restrict__ b1,
        const float* __restrict__ W2, const float* __restrict__ b2,
        const float* __restrict__ Wo, const float* __restrict__ bo,
        float* __restrict__ out, int N){
    __shared__ float row[128];
    __shared__ float g1[64];
    __shared__ float g2[32];
    const int g = blockIdx.x;
    const int t = threadIdx.x;
    int lo = 0, hi = N;
    while (lo < hi){ int m = (lo+hi)>>1; if (batch[m] < g) lo = m+1; else hi = m; }
    const int s0 = lo;
    hi = N;
    while (lo < hi){ int m = (lo+hi)>>1; if (batch[m] < g+1) lo = m+1; else hi = m; }
    const int s1 = lo;
    float acc = 0.f;
    for (int r = s0; r < s1; ++r) acc += h[(size_t)r*H + t];
    const float inv = 1.0f/fmaxf((float)(s1-s0), 1.0f);
    row[t] = acc*inv;
    __syncthreads();
    if (t < 64){
        float a = b1[t];
        #pragma unroll 4
        for (int i2=0;i2<128;i2++) a = fmaf(row[i2], W1[i2*64+t], a);
        g1[t] = fmaxf(a, 0.f);
    }
    __syncthreads();
    if (t < 32){
        float b = b2[t];
        #pragma unroll 4
        for (int i2=0;i2<64;i2++) b = fmaf(g1[i2], W2[i2*32+t], b);
        g2[t] = fmaxf(b, 0.f);
    }
    __syncthreads();
    if (t < 64){
        float p = (t < 32) ? g2[t]*Wo[t] : 0.f;
        for (int off=32; off>0; off>>=1) p += __shfl_down(p, off);
        if (t == 0) out[g] = p + bo[0];
    }
}

extern "C" void kernel_launch(void* const* d_in, const int* in_sizes, int n_in,
                              void* d_out, int out_size, void* d_ws, size_t ws_size,
                              hipStream_t stream){
    const float* x     = (const float*)d_in[0];
    const int*   eidx  = (const int*)d_in[1];
    const float* eattr = (const float*)d_in[2];
    const int*   batch = (const int*)d_in[3];
    const float* W_emb = (const float*)d_in[4];
    const float* b_emb = (const float*)d_in[5];
    const float* Wf    = (const float*)d_in[6];
    const float* bf    = (const float*)d_in[7];
    const float* Wsm   = (const float*)d_in[8];
    const float* bs    = (const float*)d_in[9];
    const float* gamma = (const float*)d_in[10];
    const float* beta  = (const float*)d_in[11];
    const float* W1    = (const float*)d_in[12];
    const float* b1    = (const float*)d_in[13];
    const float* W2    = (const float*)d_in[14];
    const float* b2    = (const float*)d_in[15];
    const float* Wo    = (const float*)d_in[16];
    const float* bo    = (const float*)d_in[17];
    float* out = (float*)d_out;

    const int N = in_sizes[0]/16;
    const int E = in_sizes[1]/2;
    const int G = out_size;

    const int* srcI = eidx;
    const int* dstI = eidx + E;

    char* p = (char*)d_ws;
    auto alloc = [&](size_t bytes)->char*{ char* r = p; p += (bytes + 255) & ~255ull; return r; };
    float*     h      = (float*)     alloc((size_t)N*H*4);
    float*     xn     = (float*)     alloc((size_t)N*H*4);
    float*     TD     = (float*)     alloc((size_t)N*2*H*4);
    _Float16*  TS16   = (_Float16*)  alloc((size_t)N*2*H*2);
    float*     ea_s   = (float*)     alloc((size_t)E*EFD*4);
    int*       src_s  = (int*)       alloc((size_t)E*4);
    int*       rowptr = (int*)       alloc((size_t)(N+1)*4);
    int*       cursor = (int*)       alloc((size_t)N*4);   // also incl-scan temp
    int*       counts = (int*)       alloc((size_t)N*4);
    int*       bsums  = (int*)       alloc(256*4);
    double*    sums   = (double*)    alloc(2*H*8);
    float*     scsh   = (float*)     alloc(2*H*4);
    s16x8*     bhi    = (s16x8*)     alloc((size_t)NLAYER*8192*16);
    s16x8*     blo    = (s16x8*)     alloc((size_t)NLAYER*8192*16);

    const int thr = 256;
    hipMemsetAsync(counts, 0, (size_t)N*4, stream);
    hipMemsetAsync(sums, 0, 2*H*8, stream);
    embed_kernel<<<(N*H + thr-1)/thr, thr, 0, stream>>>(x, W_emb, b_emb, h, N);
    hist_kernel<<<(E + thr-1)/thr, thr, 0, stream>>>(dstI, counts, E);
    int nb = (N + 1023)/1024;
    scan1<<<nb, 1024, 0, stream>>>(counts, cursor, bsums, N);
    scan2<<<1, 64, 0, stream>>>(bsums, nb);
    scan3<<<nb, 1024, 0, stream>>>(cursor, counts, bsums, rowptr, cursor, N, E);
    scatter_kernel<<<(E + thr-1)/thr, thr, 0, stream>>>(srcI, dstI, eattr, cursor, src_s, ea_s, E);
    wpack_kernel<<<128, 256, 0, stream>>>(Wf, Wsm, bhi, blo);

    for (int l=0;l<NLAYER;l++){
        const float* Wf_l = Wf  + (size_t)l*ZDIM*H;
        const float* Ws_l = Wsm + (size_t)l*ZDIM*H;
        table_mfma<<<(N+31)/32, 256, 0, stream>>>(h, bhi, blo, bf + l*H, bs + l*H, TD, TS16, N, l);
        agg_kernel<<<(N+3)/4, 256, 0, stream>>>(TD, TS16, rowptr, src_s, ea_s, Wf_l, Ws_l, h, xn, N);
        stats_kernel<<<256, 256, 0, stream>>>(xn, sums, N);
        finalize_bn<<<1, 128, 0, stream>>>(sums, gamma + l*H, beta + l*H, scsh, N);
        apply_bn<<<((N*H/4) + thr-1)/thr, thr, 0, stream>>>(xn, scsh, h, N*H/4);
    }

    pool_mlp_kernel<<<G, 128, 0, stream>>>(h, batch, W1, b1, W2, b2, Wo, bo, out, N);
}